// Round 1
// baseline (868.060 us; speedup 1.0000x reference)
//
#include <hip/hip_runtime.h>
#include <math.h>

#define BB 16
#define NN 1024
#define FIN 256
#define FH 64
#define NH 4
#define NEGV -9.0e15f

// ---------------------------------------------------------------------------
// Tiled f32 GEMM: C[M][NC] = A[M][K] * B
// MODE 0: B row-major [K][NC]
// MODE 1: B is W_heads (H, K, 64); logical col c -> head c>>6, feat c&63
// BM=BN=64, BK=16, 256 threads, 4x4 micro-tile per thread.
// ---------------------------------------------------------------------------
template <int MODE>
__global__ void gemm_kernel(const float* __restrict__ A, const float* __restrict__ Bm,
                            float* __restrict__ C, int M, int NC, int K) {
    __shared__ float As[64][16];
    __shared__ float Bs[16][65];
    const int tid = threadIdx.x;
    const int tx = tid & 15, ty = tid >> 4;
    const int row0 = blockIdx.y * 64, col0 = blockIdx.x * 64;
    float acc[4][4] = {};
    for (int k0 = 0; k0 < K; k0 += 16) {
        for (int l = tid; l < 64 * 16; l += 256) {
            int r = l >> 4, kk = l & 15;
            As[r][kk] = A[(size_t)(row0 + r) * K + k0 + kk];
        }
        for (int l = tid; l < 16 * 64; l += 256) {
            int kk = l >> 6, c = l & 63;
            int gc = col0 + c;
            size_t idx;
            if (MODE == 1) idx = (size_t)(gc >> 6) * (size_t)K * 64 + (size_t)(k0 + kk) * 64 + (gc & 63);
            else           idx = (size_t)(k0 + kk) * NC + gc;
            Bs[kk][c] = Bm[idx];
        }
        __syncthreads();
        #pragma unroll
        for (int kk = 0; kk < 16; ++kk) {
            float av[4], bv[4];
            #pragma unroll
            for (int i = 0; i < 4; ++i) av[i] = As[ty * 4 + i][kk];
            #pragma unroll
            for (int j = 0; j < 4; ++j) bv[j] = Bs[kk][tx * 4 + j];
            #pragma unroll
            for (int i = 0; i < 4; ++i)
                #pragma unroll
                for (int j = 0; j < 4; ++j)
                    acc[i][j] = fmaf(av[i], bv[j], acc[i][j]);
        }
        __syncthreads();
    }
    #pragma unroll
    for (int i = 0; i < 4; ++i)
        #pragma unroll
        for (int j = 0; j < 4; ++j)
            C[(size_t)(row0 + ty * 4 + i) * NC + col0 + tx * 4 + j] = acc[i][j];
}

// ---------------------------------------------------------------------------
// Scores: s1[gw] = Wh_row . a1 ; s2[gw] = Wh_row . a2
// One 64-lane wave per row; 4 waves (rows) per block.
// gw = h*(B*N) + bn ; Wh row at (bn*wh_stride + h*FH)
// ---------------------------------------------------------------------------
__global__ void score_kernel(const float* __restrict__ Wh, const float* __restrict__ a,
                             float* __restrict__ s1, float* __restrict__ s2,
                             int wh_stride) {
    const int gw = blockIdx.x * 4 + (threadIdx.x >> 6);
    const int lane = threadIdx.x & 63;
    const int h = gw / (BB * NN);
    const int bn = gw % (BB * NN);
    const float v = Wh[(size_t)bn * wh_stride + h * FH + lane];
    float p1 = v * a[h * 2 * FH + lane];
    float p2 = v * a[h * 2 * FH + FH + lane];
    #pragma unroll
    for (int m = 32; m >= 1; m >>= 1) {
        p1 += __shfl_xor(p1, m);
        p2 += __shfl_xor(p2, m);
    }
    if (lane == 0) { s1[gw] = p1; s2[gw] = p2; }
}

// ---------------------------------------------------------------------------
// Attention row: out[i,:] = softmax_j(mask(leakyrelu(s1_i + s2_j))) @ Wh[:, head]
// grid.x = B*N (row), grid.y = heads. 256 threads.
// ---------------------------------------------------------------------------
__global__ void attn_kernel(const float* __restrict__ Wh, int wh_stride,
                            const float* __restrict__ s1, const float* __restrict__ s2,
                            const int* __restrict__ adj,
                            float* __restrict__ out, int out_stride, int elu) {
    const int bn = blockIdx.x;
    const int h = blockIdx.y;
    const int b = bn >> 10;
    const int tid = threadIdx.x;

    __shared__ float p[NN];
    __shared__ float wredm[4];
    __shared__ float wreds[4];
    __shared__ float racc[4][64];

    const float s1i = s1[h * (BB * NN) + bn];
    const float* __restrict__ s2row = s2 + h * (BB * NN) + b * NN;
    const int* __restrict__ adjrow = adj + (size_t)bn * NN;

    // pass 1: e_j with leaky-relu + mask; running max
    float mx = -INFINITY;
    for (int j = tid; j < NN; j += 256) {
        float e = s1i + s2row[j];
        e = (e > 0.f) ? e : 0.2f * e;
        e = (adjrow[j] > 0) ? e : NEGV;
        p[j] = e;
        mx = fmaxf(mx, e);
    }
    #pragma unroll
    for (int m = 32; m >= 1; m >>= 1) mx = fmaxf(mx, __shfl_xor(mx, m));
    if ((tid & 63) == 0) wredm[tid >> 6] = mx;
    __syncthreads();
    mx = fmaxf(fmaxf(wredm[0], wredm[1]), fmaxf(wredm[2], wredm[3]));

    // pass 2: exp + sum (same-thread j's, no barrier needed for p)
    float sum = 0.f;
    for (int j = tid; j < NN; j += 256) {
        float v = expf(p[j] - mx);
        p[j] = v;
        sum += v;
    }
    #pragma unroll
    for (int m = 32; m >= 1; m >>= 1) sum += __shfl_xor(sum, m);
    if ((tid & 63) == 0) wreds[tid >> 6] = sum;
    __syncthreads();
    const float inv = 1.f / (wreds[0] + wreds[1] + wreds[2] + wreds[3]);
    for (int j = tid; j < NN; j += 256) p[j] *= inv;
    __syncthreads();

    // weighted accumulation: 4 waves split j, 64 lanes = features
    const int f = tid & 63, g = tid >> 6;
    float acc = 0.f;
    const float* __restrict__ whc = Wh + (size_t)(b * NN) * wh_stride + h * FH + f;
    #pragma unroll 8
    for (int j = g; j < NN; j += 4)
        acc = fmaf(p[j], whc[(size_t)j * wh_stride], acc);
    racc[g][f] = acc;
    __syncthreads();
    if (g == 0) {
        float r = racc[0][f] + racc[1][f] + racc[2][f] + racc[3][f];
        if (elu) r = (r > 0.f) ? r : (expf(r) - 1.f);
        out[(size_t)bn * out_stride + h * FH + f] = r;
    }
}

// ---------------------------------------------------------------------------
// Mean over axis=1: out[b][f] = (1/N) sum_i out2[b][i][f]
// ---------------------------------------------------------------------------
__global__ void mean_kernel(const float* __restrict__ out2, float* __restrict__ out) {
    const int b = blockIdx.x;
    const int f = threadIdx.x & 63, g = threadIdx.x >> 6;
    float acc = 0.f;
    #pragma unroll 8
    for (int i = g; i < NN; i += 4)
        acc += out2[((size_t)b * NN + i) * FH + f];
    __shared__ float r[4][64];
    r[g][f] = acc;
    __syncthreads();
    if (g == 0)
        out[b * FH + f] = (r[0][f] + r[1][f] + r[2][f] + r[3][f]) * (1.0f / NN);
}

extern "C" void kernel_launch(void* const* d_in, const int* in_sizes, int n_in,
                              void* d_out, int out_size, void* d_ws, size_t ws_size,
                              hipStream_t stream) {
    const float* x       = (const float*)d_in[0];
    const int*   adj     = (const int*)d_in[1];
    const float* W_heads = (const float*)d_in[2];
    const float* a_heads = (const float*)d_in[3];
    const float* W_out   = (const float*)d_in[4];
    const float* a_out   = (const float*)d_in[5];
    float* out = (float*)d_out;
    float* ws  = (float*)d_ws;

    // workspace layout (floats)
    float* Wh1  = ws;                 // [16384][256]  (b,n, h*64+f)
    float* hcat = ws + 4194304;       // [16384][256]
    float* s1_1 = ws + 8388608;       // [4*16384]
    float* s2_1 = s1_1 + 65536;
    float* s1_2 = s2_1 + 65536;       // [16384]
    float* s2_2 = s1_2 + 16384;
    float* Wh2  = Wh1;                // alias: Wh1 dead after layer-1 attention
    float* out2 = Wh1 + 1048576;      // alias region, disjoint from Wh2

    dim3 blk(256);

    // layer 1
    gemm_kernel<1><<<dim3(256 / 64, 16384 / 64), blk, 0, stream>>>(x, W_heads, Wh1, 16384, 256, 256);
    score_kernel<<<dim3(NH * BB * NN / 4), blk, 0, stream>>>(Wh1, a_heads, s1_1, s2_1, 256);
    attn_kernel<<<dim3(BB * NN, NH), blk, 0, stream>>>(Wh1, 256, s1_1, s2_1, adj, hcat, 256, 0);

    // layer 2
    gemm_kernel<0><<<dim3(64 / 64, 16384 / 64), blk, 0, stream>>>(hcat, W_out, Wh2, 16384, 64, 256);
    score_kernel<<<dim3(BB * NN / 4), blk, 0, stream>>>(Wh2, a_out, s1_2, s2_2, 64);
    attn_kernel<<<dim3(BB * NN, 1), blk, 0, stream>>>(Wh2, 64, s1_2, s2_2, adj, out2, 64, 1);

    // mean over nodes
    mean_kernel<<<dim3(BB), blk, 0, stream>>>(out2, out);
}

// Round 2
// 331.875 us; speedup vs baseline: 2.6156x; 2.6156x over previous
//
#include <hip/hip_runtime.h>
#include <math.h>

#define BB 16
#define NN 1024
#define FIN 256
#define FH 64
#define NH 4
#define NEGV -9.0e15f
#define LOG2E 1.4426950408889634f

typedef __attribute__((ext_vector_type(8))) short short8;
typedef __attribute__((ext_vector_type(4))) float f32x4;

__device__ inline unsigned short f2bf(float x) {
    unsigned int u = __builtin_bit_cast(unsigned int, x);
    u += 0x7fff + ((u >> 16) & 1);   // round-to-nearest-even
    return (unsigned short)(u >> 16);
}

// ---------------------------------------------------------------------------
// Tiled f32 GEMM: C[M][NC] = A[M][K] * B   (unchanged from round 1)
// MODE 0: B row-major [K][NC];  MODE 1: B is W_heads (H, K, 64)
// ---------------------------------------------------------------------------
template <int MODE>
__global__ void gemm_kernel(const float* __restrict__ A, const float* __restrict__ Bm,
                            float* __restrict__ C, int M, int NC, int K) {
    __shared__ float As[64][16];
    __shared__ float Bs[16][65];
    const int tid = threadIdx.x;
    const int tx = tid & 15, ty = tid >> 4;
    const int row0 = blockIdx.y * 64, col0 = blockIdx.x * 64;
    float acc[4][4] = {};
    for (int k0 = 0; k0 < K; k0 += 16) {
        for (int l = tid; l < 64 * 16; l += 256) {
            int r = l >> 4, kk = l & 15;
            As[r][kk] = A[(size_t)(row0 + r) * K + k0 + kk];
        }
        for (int l = tid; l < 16 * 64; l += 256) {
            int kk = l >> 6, c = l & 63;
            int gc = col0 + c;
            size_t idx;
            if (MODE == 1) idx = (size_t)(gc >> 6) * (size_t)K * 64 + (size_t)(k0 + kk) * 64 + (gc & 63);
            else           idx = (size_t)(k0 + kk) * NC + gc;
            Bs[kk][c] = Bm[idx];
        }
        __syncthreads();
        #pragma unroll
        for (int kk = 0; kk < 16; ++kk) {
            float av[4], bv[4];
            #pragma unroll
            for (int i = 0; i < 4; ++i) av[i] = As[ty * 4 + i][kk];
            #pragma unroll
            for (int j = 0; j < 4; ++j) bv[j] = Bs[kk][tx * 4 + j];
            #pragma unroll
            for (int i = 0; i < 4; ++i)
                #pragma unroll
                for (int j = 0; j < 4; ++j)
                    acc[i][j] = fmaf(av[i], bv[j], acc[i][j]);
        }
        __syncthreads();
    }
    #pragma unroll
    for (int i = 0; i < 4; ++i)
        #pragma unroll
        for (int j = 0; j < 4; ++j)
            C[(size_t)(row0 + ty * 4 + i) * NC + col0 + tx * 4 + j] = acc[i][j];
}

// ---------------------------------------------------------------------------
// Scores: s1[gw] = Wh_row . a1 ; s2[gw] = Wh_row . a2  (unchanged)
// ---------------------------------------------------------------------------
__global__ void score_kernel(const float* __restrict__ Wh, const float* __restrict__ a,
                             float* __restrict__ s1, float* __restrict__ s2,
                             int wh_stride) {
    const int gw = blockIdx.x * 4 + (threadIdx.x >> 6);
    const int lane = threadIdx.x & 63;
    const int h = gw / (BB * NN);
    const int bn = gw % (BB * NN);
    const float v = Wh[(size_t)bn * wh_stride + h * FH + lane];
    float p1 = v * a[h * 2 * FH + lane];
    float p2 = v * a[h * 2 * FH + FH + lane];
    #pragma unroll
    for (int m = 32; m >= 1; m >>= 1) {
        p1 += __shfl_xor(p1, m);
        p2 += __shfl_xor(p2, m);
    }
    if (lane == 0) { s1[gw] = p1; s2[gw] = p2; }
}

// ---------------------------------------------------------------------------
// Softmax stats per row: m2 = max*log2e, inv = 1/sum(exp(e-max))
// One block per row (b*N+i); 256 threads x 4 j's = 1024. Loop over H heads.
// ---------------------------------------------------------------------------
template <int H>
__global__ void stats_kernel(const float* __restrict__ s1, const float* __restrict__ s2,
                             const int* __restrict__ adj,
                             float* __restrict__ m2s, float* __restrict__ invs) {
    const int row = blockIdx.x;          // b*N + i
    const int b = row >> 10;
    const int tid = threadIdx.x;
    __shared__ float red[4];
    const int4 a4 = *(const int4*)(adj + (size_t)row * NN + tid * 4);
    #pragma unroll
    for (int h = 0; h < H; ++h) {
        const int hb = h * (BB * NN);
        const float s1i = s1[hb + row];
        const float4 s2v = *(const float4*)(s2 + hb + b * NN + tid * 4);
        float e0 = s1i + s2v.x; e0 = fmaxf(e0, 0.2f * e0); e0 = (a4.x > 0) ? e0 : NEGV;
        float e1 = s1i + s2v.y; e1 = fmaxf(e1, 0.2f * e1); e1 = (a4.y > 0) ? e1 : NEGV;
        float e2 = s1i + s2v.z; e2 = fmaxf(e2, 0.2f * e2); e2 = (a4.z > 0) ? e2 : NEGV;
        float e3 = s1i + s2v.w; e3 = fmaxf(e3, 0.2f * e3); e3 = (a4.w > 0) ? e3 : NEGV;
        float mx = fmaxf(fmaxf(e0, e1), fmaxf(e2, e3));
        #pragma unroll
        for (int m = 32; m >= 1; m >>= 1) mx = fmaxf(mx, __shfl_xor(mx, m));
        if ((tid & 63) == 0) red[tid >> 6] = mx;
        __syncthreads();
        mx = fmaxf(fmaxf(red[0], red[1]), fmaxf(red[2], red[3]));
        __syncthreads();
        float s = __builtin_amdgcn_exp2f((e0 - mx) * LOG2E)
                + __builtin_amdgcn_exp2f((e1 - mx) * LOG2E)
                + __builtin_amdgcn_exp2f((e2 - mx) * LOG2E)
                + __builtin_amdgcn_exp2f((e3 - mx) * LOG2E);
        #pragma unroll
        for (int m = 32; m >= 1; m >>= 1) s += __shfl_xor(s, m);
        if ((tid & 63) == 0) red[tid >> 6] = s;
        __syncthreads();
        s = red[0] + red[1] + red[2] + red[3];
        if (tid == 0) {
            m2s[hb + row]  = mx * LOG2E;
            invs[hb + row] = 1.0f / s;
        }
        __syncthreads();
    }
}

// ---------------------------------------------------------------------------
// Fused attention apply: O^T = Wh^T . P^T via mfma_f32_16x16x32_bf16.
// Block = 64 i-rows x 64 feats for one (b,h). 4 waves; wave w owns i-block w
// (its own P rows -> B fragments), all waves load the 4 shared A (Wh^T)
// fragments (same addresses -> L1 hits). P generated on the fly.
// ---------------------------------------------------------------------------
__global__ void apply_kernel(const float* __restrict__ Wh, int whs,
                             const float* __restrict__ s1, const float* __restrict__ s2,
                             const float* __restrict__ m2s, const float* __restrict__ invs,
                             const int* __restrict__ adj,
                             float* __restrict__ out, int ostride, int do_elu) {
    const int it = blockIdx.x;            // i-tile (64 rows)
    const int b  = blockIdx.y;
    const int h  = blockIdx.z;
    const int tid = threadIdx.x;
    const int w  = tid >> 6;              // wave -> i-block
    const int l  = tid & 63;
    const int lo = l & 15, kg = l >> 4;
    const int i0 = it * 64;
    const int hb = h * (BB * NN) + b * NN;

    // per-lane row constants (row = i0 + w*16 + lo)
    const int iloc = w * 16 + lo;
    const float s1i  = s1[hb + i0 + iloc];
    const float nm2  = -m2s[hb + i0 + iloc];
    const float invi = invs[hb + i0 + iloc];
    const int* __restrict__ adjrow = adj + ((size_t)(b * NN + i0 + iloc)) * NN;

    const float* __restrict__ whb = Wh + (size_t)(b * NN) * whs + h * FH;
    const float* __restrict__ s2p = s2 + hb;

    f32x4 acc[4];
    #pragma unroll
    for (int fb = 0; fb < 4; ++fb) acc[fb] = (f32x4){0.f, 0.f, 0.f, 0.f};

    for (int j0 = 0; j0 < NN; j0 += 32) {
        const int kbase = j0 + kg * 8;
        // B fragment: P^T[k][i] for this wave's i
        const int4 aa = *(const int4*)(adjrow + kbase);
        const int4 ab = *(const int4*)(adjrow + kbase + 4);
        const float4 sa = *(const float4*)(s2p + kbase);
        const float4 sb = *(const float4*)(s2p + kbase + 4);
        float s2r[8] = {sa.x, sa.y, sa.z, sa.w, sb.x, sb.y, sb.z, sb.w};
        int   ar[8]  = {aa.x, aa.y, aa.z, aa.w, ab.x, ab.y, ab.z, ab.w};
        short8 bfr;
        #pragma unroll
        for (int e = 0; e < 8; ++e) {
            float ev = s1i + s2r[e];
            ev = fmaxf(ev, 0.2f * ev);
            ev = (ar[e] > 0) ? ev : NEGV;
            float t = __builtin_fmaf(ev, LOG2E, nm2);
            float p = __builtin_amdgcn_exp2f(t) * invi;
            bfr[e] = (short)f2bf(p);
        }
        // A fragments: Wh^T[f][k] = Wh[j0+kg*8+e][f], f = fb*16 + lo
        const float* wp = whb + (size_t)kbase * whs + lo;
        #pragma unroll
        for (int fb = 0; fb < 4; ++fb) {
            short8 afr;
            #pragma unroll
            for (int e = 0; e < 8; ++e)
                afr[e] = (short)f2bf(wp[(size_t)e * whs + fb * 16]);
            acc[fb] = __builtin_amdgcn_mfma_f32_16x16x32_bf16(afr, bfr, acc[fb], 0, 0, 0);
        }
    }

    // D layout: col(=i) = lane&15, row(=f) = (lane>>4)*4 + r
    const size_t orow = (size_t)(b * NN + i0 + iloc) * ostride + h * FH;
    #pragma unroll
    for (int fb = 0; fb < 4; ++fb) {
        #pragma unroll
        for (int r = 0; r < 4; ++r) {
            float v = acc[fb][r];
            if (do_elu) v = (v > 0.f) ? v : (__builtin_amdgcn_exp2f(v * LOG2E) - 1.0f);
            out[orow + fb * 16 + kg * 4 + r] = v;
        }
    }
}

// ---------------------------------------------------------------------------
// Mean over axis=1 (unchanged)
// ---------------------------------------------------------------------------
__global__ void mean_kernel(const float* __restrict__ out2, float* __restrict__ out) {
    const int b = blockIdx.x;
    const int f = threadIdx.x & 63, g = threadIdx.x >> 6;
    float acc = 0.f;
    #pragma unroll 8
    for (int i = g; i < NN; i += 4)
        acc += out2[((size_t)b * NN + i) * FH + f];
    __shared__ float r[4][64];
    r[g][f] = acc;
    __syncthreads();
    if (g == 0)
        out[b * FH + f] = (r[0][f] + r[1][f] + r[2][f] + r[3][f]) * (1.0f / NN);
}

extern "C" void kernel_launch(void* const* d_in, const int* in_sizes, int n_in,
                              void* d_out, int out_size, void* d_ws, size_t ws_size,
                              hipStream_t stream) {
    const float* x       = (const float*)d_in[0];
    const int*   adj     = (const int*)d_in[1];
    const float* W_heads = (const float*)d_in[2];
    const float* a_heads = (const float*)d_in[3];
    const float* W_out   = (const float*)d_in[4];
    const float* a_out   = (const float*)d_in[5];
    float* out = (float*)d_out;
    float* ws  = (float*)d_ws;

    // workspace layout (floats)
    float* Wh1  = ws;                  // [16384][256]
    float* hcat = ws + 4194304;        // [16384][256]
    float* s1_1 = ws + 8388608;        // [4][16384]
    float* s2_1 = s1_1 + 65536;        // [4][16384]
    float* s1_2 = s2_1 + 65536;        // [16384]
    float* s2_2 = s1_2 + 16384;        // [16384]
    float* m2_1 = s2_2 + 16384;        // [4][16384]
    float* inv_1 = m2_1 + 65536;       // [4][16384]
    float* m2_2 = inv_1 + 65536;       // [16384]
    float* inv_2 = m2_2 + 16384;       // [16384]
    float* Wh2  = Wh1;                 // alias: Wh1 dead after layer-1 apply
    float* out2 = Wh1 + 1048576;       // alias region, disjoint from Wh2

    dim3 blk(256);

    // layer 1
    gemm_kernel<1><<<dim3(4, 256), blk, 0, stream>>>(x, W_heads, Wh1, 16384, 256, 256);
    score_kernel<<<dim3(NH * BB * NN / 4), blk, 0, stream>>>(Wh1, a_heads, s1_1, s2_1, 256);
    stats_kernel<NH><<<dim3(BB * NN), blk, 0, stream>>>(s1_1, s2_1, adj, m2_1, inv_1);
    apply_kernel<<<dim3(16, BB, NH), blk, 0, stream>>>(Wh1, 256, s1_1, s2_1, m2_1, inv_1, adj, hcat, 256, 0);

    // layer 2
    gemm_kernel<0><<<dim3(1, 256), blk, 0, stream>>>(hcat, W_out, Wh2, 16384, 64, 256);
    score_kernel<<<dim3(BB * NN / 4), blk, 0, stream>>>(Wh2, a_out, s1_2, s2_2, 64);
    stats_kernel<1><<<dim3(BB * NN), blk, 0, stream>>>(s1_2, s2_2, adj, m2_2, inv_2);
    apply_kernel<<<dim3(16, BB, 1), blk, 0, stream>>>(Wh2, 64, s1_2, s2_2, m2_2, inv_2, adj, out2, 64, 1);

    // mean over nodes
    mean_kernel<<<dim3(BB), blk, 0, stream>>>(out2, out);
}

// Round 3
// 253.863 us; speedup vs baseline: 3.4194x; 1.3073x over previous
//
#include <hip/hip_runtime.h>
#include <math.h>

#define BB 16
#define NN 1024
#define FH 64
#define NH 4
#define LOG2E 1.4426950408889634f

typedef __attribute__((ext_vector_type(8))) short short8;
typedef __attribute__((ext_vector_type(4))) float f32x4;
typedef unsigned long long u64;
typedef unsigned short ushort_t;

__device__ inline unsigned short f2bf(float x) {
    unsigned int u = __builtin_bit_cast(unsigned int, x);
    u += 0x7fff + ((u >> 16) & 1);   // round-to-nearest-even
    return (unsigned short)(u >> 16);
}

// ---------------------------------------------------------------------------
// adj -> bitmask. bm[row][g] bit l = adj[row*1024 + g*64 + l] > 0.
// 4 waves/block, one row per wave.
// ---------------------------------------------------------------------------
__global__ void pack_kernel(const int* __restrict__ adj, u64* __restrict__ bm) {
    const int row = blockIdx.x * 4 + (threadIdx.x >> 6);
    const int lane = threadIdx.x & 63;
    const int* __restrict__ ar = adj + (size_t)row * NN;
    #pragma unroll
    for (int g = 0; g < 16; ++g) {
        u64 m = __ballot(ar[g * 64 + lane] > 0);
        if (lane == 0) bm[row * 16 + g] = m;
    }
}

// ---------------------------------------------------------------------------
// Pack weights transposed to bf16: BT[col][k].
// cols 0..255 -> layer-1 (W_heads[h][k][f], col=h*64+f); 256..319 -> layer-2.
// ---------------------------------------------------------------------------
__global__ void packw_kernel(const float* __restrict__ Whd, const float* __restrict__ Wo,
                             ushort_t* __restrict__ BT1, ushort_t* __restrict__ BT2) {
    const int col = blockIdx.x, k = threadIdx.x;
    if (col < 256) BT1[col * 256 + k] = f2bf(Whd[(col >> 6) * 16384 + k * 64 + (col & 63)]);
    else           BT2[(col - 256) * 256 + k] = f2bf(Wo[k * 64 + (col - 256)]);
}

// ---------------------------------------------------------------------------
// MFMA GEMM: C[M][NC] f32 = A[M][K] f32 (cvt to bf16) x BT[NC][K] bf16.
// Block 64 rows x 64 cols, 4 waves (wave w = rows w*16..), K=256.
// ---------------------------------------------------------------------------
__global__ void gemm_mfma(const float* __restrict__ A, const ushort_t* __restrict__ BT,
                          float* __restrict__ C, int NC) {
    const int K = 256;
    const int tid = threadIdx.x;
    const int w = tid >> 6, l = tid & 63, lo = l & 15, kg = l >> 4;
    const int row0 = blockIdx.y * 64, col0 = blockIdx.x * 64;
    const float* __restrict__ arow = A + (size_t)(row0 + w * 16 + lo) * K;
    f32x4 acc[4];
    #pragma unroll
    for (int cb = 0; cb < 4; ++cb) acc[cb] = (f32x4){0.f, 0.f, 0.f, 0.f};
    #pragma unroll
    for (int ks = 0; ks < 8; ++ks) {
        const int k0 = ks * 32 + kg * 8;
        const float4 a0 = *(const float4*)(arow + k0);
        const float4 a1 = *(const float4*)(arow + k0 + 4);
        short8 af;
        af[0] = (short)f2bf(a0.x); af[1] = (short)f2bf(a0.y);
        af[2] = (short)f2bf(a0.z); af[3] = (short)f2bf(a0.w);
        af[4] = (short)f2bf(a1.x); af[5] = (short)f2bf(a1.y);
        af[6] = (short)f2bf(a1.z); af[7] = (short)f2bf(a1.w);
        #pragma unroll
        for (int cb = 0; cb < 4; ++cb) {
            const short8 bf = *(const short8*)(BT + (size_t)(col0 + cb * 16 + lo) * K + k0);
            acc[cb] = __builtin_amdgcn_mfma_f32_16x16x32_bf16(af, bf, acc[cb], 0, 0, 0);
        }
    }
    #pragma unroll
    for (int cb = 0; cb < 4; ++cb)
        #pragma unroll
        for (int r = 0; r < 4; ++r)
            C[(size_t)(row0 + w * 16 + kg * 4 + r) * NC + col0 + cb * 16 + lo] = acc[cb][r];
}

// ---------------------------------------------------------------------------
// Scores: s1[gw] = Wh_row . a1 ; s2[gw] = Wh_row . a2
// ---------------------------------------------------------------------------
__global__ void score_kernel(const float* __restrict__ Wh, const float* __restrict__ a,
                             float* __restrict__ s1, float* __restrict__ s2,
                             int wh_stride) {
    const int gw = blockIdx.x * 4 + (threadIdx.x >> 6);
    const int lane = threadIdx.x & 63;
    const int h = gw / (BB * NN);
    const int bn = gw % (BB * NN);
    const float v = Wh[(size_t)bn * wh_stride + h * FH + lane];
    float p1 = v * a[h * 2 * FH + lane];
    float p2 = v * a[h * 2 * FH + FH + lane];
    #pragma unroll
    for (int m = 32; m >= 1; m >>= 1) {
        p1 += __shfl_xor(p1, m);
        p2 += __shfl_xor(p2, m);
    }
    if (lane == 0) { s1[gw] = p1; s2[gw] = p2; }
}

// ---------------------------------------------------------------------------
// Transpose Wh f32 [B*N][S] -> WhbT bf16 [b][S][1024].
// ---------------------------------------------------------------------------
__global__ void transpose_kernel(const float* __restrict__ Wh, int S,
                                 ushort_t* __restrict__ WhbT) {
    __shared__ ushort_t t[64][65];
    const int tid = threadIdx.x;
    const int j0 = blockIdx.x * 64, f0 = blockIdx.y * 64, b = blockIdx.z;
    const float* __restrict__ src = Wh + ((size_t)(b * NN + j0)) * S + f0;
    for (int lidx = tid; lidx < 4096; lidx += 256) {
        int r = lidx >> 6, c = lidx & 63;       // r = j-local, c = f-local
        t[c][r] = f2bf(src[(size_t)r * S + c]);
    }
    __syncthreads();
    ushort_t* __restrict__ dst = WhbT + ((size_t)(b * S + f0)) * NN + j0;
    for (int lidx = tid; lidx < 4096; lidx += 256) {
        int r = lidx >> 6, c = lidx & 63;       // r = f-local, c = j-local
        dst[(size_t)r * NN + c] = t[r][c];
    }
}

// ---------------------------------------------------------------------------
// Softmax stats per row from bitmask: m2 = max*log2e, inv = 1/sum(exp(e-max)).
// ---------------------------------------------------------------------------
template <int H>
__global__ void stats_kernel(const float* __restrict__ s1, const float* __restrict__ s2,
                             const u64* __restrict__ bm,
                             float* __restrict__ m2s, float* __restrict__ invs) {
    const int row = blockIdx.x;          // b*N + i
    const int b = row >> 10;
    const int tid = threadIdx.x;
    __shared__ float red[4];
    const unsigned bits = (unsigned)(bm[row * 16 + (tid >> 4)] >> ((tid & 15) * 4)) & 0xF;
    #pragma unroll
    for (int h = 0; h < H; ++h) {
        const int hb = h * (BB * NN);
        const float s1i = s1[hb + row];
        const float4 s2v = *(const float4*)(s2 + hb + b * NN + tid * 4);
        float e0 = s1i + s2v.x; e0 = fmaxf(e0, 0.2f * e0); e0 = (bits & 1) ? e0 : -9.0e15f;
        float e1 = s1i + s2v.y; e1 = fmaxf(e1, 0.2f * e1); e1 = (bits & 2) ? e1 : -9.0e15f;
        float e2 = s1i + s2v.z; e2 = fmaxf(e2, 0.2f * e2); e2 = (bits & 4) ? e2 : -9.0e15f;
        float e3 = s1i + s2v.w; e3 = fmaxf(e3, 0.2f * e3); e3 = (bits & 8) ? e3 : -9.0e15f;
        float mx = fmaxf(fmaxf(e0, e1), fmaxf(e2, e3));
        #pragma unroll
        for (int m = 32; m >= 1; m >>= 1) mx = fmaxf(mx, __shfl_xor(mx, m));
        if ((tid & 63) == 0) red[tid >> 6] = mx;
        __syncthreads();
        mx = fmaxf(fmaxf(red[0], red[1]), fmaxf(red[2], red[3]));
        __syncthreads();
        float s = __builtin_amdgcn_exp2f((e0 - mx) * LOG2E)
                + __builtin_amdgcn_exp2f((e1 - mx) * LOG2E)
                + __builtin_amdgcn_exp2f((e2 - mx) * LOG2E)
                + __builtin_amdgcn_exp2f((e3 - mx) * LOG2E);
        #pragma unroll
        for (int m = 32; m >= 1; m >>= 1) s += __shfl_xor(s, m);
        if ((tid & 63) == 0) red[tid >> 6] = s;
        __syncthreads();
        s = red[0] + red[1] + red[2] + red[3];
        if (tid == 0) {
            m2s[hb + row]  = mx * LOG2E;
            invs[hb + row] = 1.0f / s;
        }
        __syncthreads();
    }
}

// ---------------------------------------------------------------------------
// Fused attention apply: O^T = Wh^T . P^T via mfma_f32_16x16x32_bf16.
// A-frag = one short8 load from WhbT[b][f][j]; P generated on the fly from
// scores + bitmask. Block = 64 i x 64 f for one (b,h); wave w owns i-block w.
// ---------------------------------------------------------------------------
__global__ void apply_kernel(const ushort_t* __restrict__ WhbT, int S,
                             const float* __restrict__ s1, const float* __restrict__ s2,
                             const float* __restrict__ m2s, const float* __restrict__ invs,
                             const u64* __restrict__ bm,
                             float* __restrict__ out, int ostride, int do_elu) {
    const int it = blockIdx.x;
    const int b  = blockIdx.y;
    const int h  = blockIdx.z;
    const int tid = threadIdx.x;
    const int w  = tid >> 6;
    const int l  = tid & 63;
    const int lo = l & 15, kg = l >> 4;
    const int i0 = it * 64;
    const int iloc = w * 16 + lo;
    const int gi = b * NN + i0 + iloc;
    const int hb = h * (BB * NN) + b * NN;

    const float s1i  = s1[h * (BB * NN) + gi - b * NN + b * NN]; // = s1[h*BB*NN + gi]
    const float nm2  = -m2s[h * (BB * NN) + gi];
    const float invi = invs[h * (BB * NN) + gi];
    const u64* __restrict__ bmrow = bm + (size_t)gi * 16;
    const float* __restrict__ s2p = s2 + hb;
    const ushort_t* __restrict__ whb = WhbT + (size_t)(b * S + h * FH) * NN;

    f32x4 acc[4];
    #pragma unroll
    for (int fb = 0; fb < 4; ++fb) acc[fb] = (f32x4){0.f, 0.f, 0.f, 0.f};

    for (int j0 = 0; j0 < NN; j0 += 32) {
        const int kbase = j0 + kg * 8;
        const unsigned bits = (unsigned)(bmrow[kbase >> 6] >> (kbase & 63)) & 0xFF;
        const float4 sa = *(const float4*)(s2p + kbase);
        const float4 sb = *(const float4*)(s2p + kbase + 4);
        const float s2r[8] = {sa.x, sa.y, sa.z, sa.w, sb.x, sb.y, sb.z, sb.w};
        short8 bfr;
        #pragma unroll
        for (int e = 0; e < 8; ++e) {
            float ev = s1i + s2r[e];
            ev = fmaxf(ev, 0.2f * ev);
            float p = __builtin_amdgcn_exp2f(__builtin_fmaf(ev, LOG2E, nm2)) * invi;
            p = ((bits >> e) & 1) ? p : 0.f;
            bfr[e] = (short)f2bf(p);
        }
        #pragma unroll
        for (int fb = 0; fb < 4; ++fb) {
            const short8 afr = *(const short8*)(whb + (size_t)(fb * 16 + lo) * NN + kbase);
            acc[fb] = __builtin_amdgcn_mfma_f32_16x16x32_bf16(afr, bfr, acc[fb], 0, 0, 0);
        }
    }

    // D layout: col(=i) = lane&15, row(=f) = (lane>>4)*4 + r
    const size_t orow = (size_t)gi * ostride + h * FH;
    #pragma unroll
    for (int fb = 0; fb < 4; ++fb) {
        #pragma unroll
        for (int r = 0; r < 4; ++r) {
            float v = acc[fb][r];
            if (do_elu) v = (v > 0.f) ? v : (__builtin_amdgcn_exp2f(v * LOG2E) - 1.0f);
            out[orow + fb * 16 + kg * 4 + r] = v;
        }
    }
}

// ---------------------------------------------------------------------------
// Mean over axis=1
// ---------------------------------------------------------------------------
__global__ void mean_kernel(const float* __restrict__ out2, float* __restrict__ out) {
    const int b = blockIdx.x;
    const int f = threadIdx.x & 63, g = threadIdx.x >> 6;
    float acc = 0.f;
    #pragma unroll 8
    for (int i = g; i < NN; i += 4)
        acc += out2[((size_t)b * NN + i) * FH + f];
    __shared__ float r[4][64];
    r[g][f] = acc;
    __syncthreads();
    if (g == 0)
        out[b * FH + f] = (r[0][f] + r[1][f] + r[2][f] + r[3][f]) * (1.0f / NN);
}

extern "C" void kernel_launch(void* const* d_in, const int* in_sizes, int n_in,
                              void* d_out, int out_size, void* d_ws, size_t ws_size,
                              hipStream_t stream) {
    const float* x       = (const float*)d_in[0];
    const int*   adj     = (const int*)d_in[1];
    const float* W_heads = (const float*)d_in[2];
    const float* a_heads = (const float*)d_in[3];
    const float* W_out   = (const float*)d_in[4];
    const float* a_out   = (const float*)d_in[5];
    float* out = (float*)d_out;
    float* f0  = (float*)d_ws;

    // workspace layout (float offsets)
    float*    RegA   = f0;                               // 4,194,304 f: Wh1 then hcat
    ushort_t* WhbT1  = (ushort_t*)(f0 + 4194304);        // 4,194,304 bf16 (dead after apply1)
    float*    out2   = f0 + 4194304;                     // alias over WhbT1 region
    float*    Wh2    = f0 + 6291456;                     // 1,048,576 f
    ushort_t* WhbT2  = (ushort_t*)(f0 + 7340032);        // 1,048,576 bf16
    u64*      bmask  = (u64*)(f0 + 7864320);             // 262,144 u64
    ushort_t* WbT1   = (ushort_t*)(f0 + 8388608);        // 65,536 bf16
    ushort_t* WbT2   = (ushort_t*)(f0 + 8421376);        // 16,384 bf16
    float*    s1_1   = f0 + 8429568;                     // 65,536
    float*    s2_1   = s1_1 + 65536;                     // 65,536
    float*    m2_1   = s2_1 + 65536;                     // 65,536
    float*    inv_1  = m2_1 + 65536;                     // 65,536
    float*    s1_2   = s1_1;                             // alias (layer-1 dead)
    float*    s2_2   = s2_1;
    float*    m2_2   = m2_1;
    float*    inv_2  = inv_1;
    float*    Wh1    = RegA;
    float*    hcat   = RegA;

    dim3 blk(256);

    // shared pre-passes
    pack_kernel<<<dim3(BB * NN / 4), blk, 0, stream>>>(adj, bmask);
    packw_kernel<<<dim3(320), blk, 0, stream>>>(W_heads, W_out, WbT1, WbT2);

    // layer 1
    gemm_mfma<<<dim3(4, 256), blk, 0, stream>>>(x, WbT1, Wh1, 256);
    score_kernel<<<dim3(NH * BB * NN / 4), blk, 0, stream>>>(Wh1, a_heads, s1_1, s2_1, 256);
    transpose_kernel<<<dim3(16, 4, BB), blk, 0, stream>>>(Wh1, 256, WhbT1);
    stats_kernel<NH><<<dim3(BB * NN), blk, 0, stream>>>(s1_1, s2_1, bmask, m2_1, inv_1);
    apply_kernel<<<dim3(16, BB, NH), blk, 0, stream>>>(WhbT1, 256, s1_1, s2_1, m2_1, inv_1, bmask, hcat, 256, 0);

    // layer 2
    gemm_mfma<<<dim3(1, 256), blk, 0, stream>>>(hcat, WbT2, Wh2, 64);
    score_kernel<<<dim3(BB * NN / 4), blk, 0, stream>>>(Wh2, a_out, s1_2, s2_2, 64);
    transpose_kernel<<<dim3(16, 1, BB), blk, 0, stream>>>(Wh2, 64, WhbT2);
    stats_kernel<1><<<dim3(BB * NN), blk, 0, stream>>>(s1_2, s2_2, bmask, m2_2, inv_2);
    apply_kernel<<<dim3(16, BB, 1), blk, 0, stream>>>(WhbT2, 64, s1_2, s2_2, m2_2, inv_2, bmask, out2, 64, 1);

    // mean over nodes
    mean_kernel<<<dim3(BB), blk, 0, stream>>>(out2, out);
}

// Round 4
// 220.746 us; speedup vs baseline: 3.9324x; 1.1500x over previous
//
#include <hip/hip_runtime.h>
#include <math.h>

#define BB 16
#define NN 1024
#define FH 64
#define NH 4
#define NEGV -9.0e15f
#define LOG2E 1.4426950408889634f

typedef __attribute__((ext_vector_type(8))) short short8;
typedef __attribute__((ext_vector_type(4))) float f32x4;
typedef unsigned long long u64;
typedef unsigned short ushort_t;

__device__ inline unsigned f2bf(float x) {
    unsigned u = __builtin_bit_cast(unsigned, x);
    u += 0x7fff + ((u >> 16) & 1);   // round-to-nearest-even
    return u >> 16;
}

// ---------------------------------------------------------------------------
// adj -> bitmask. bm[row][g] bit l = adj[row*1024 + g*64 + l] > 0.
// ---------------------------------------------------------------------------
__global__ void pack_kernel(const int* __restrict__ adj, u64* __restrict__ bm) {
    const int row = blockIdx.x * 4 + (threadIdx.x >> 6);
    const int lane = threadIdx.x & 63;
    const int* __restrict__ ar = adj + (size_t)row * NN;
    #pragma unroll
    for (int g = 0; g < 16; ++g) {
        u64 m = __ballot(ar[g * 64 + lane] > 0);
        if (lane == 0) bm[row * 16 + g] = m;
    }
}

// ---------------------------------------------------------------------------
// Pack weights transposed to bf16: BT[col][k].
// ---------------------------------------------------------------------------
__global__ void packw_kernel(const float* __restrict__ Whd, const float* __restrict__ Wo,
                             ushort_t* __restrict__ BT1, ushort_t* __restrict__ BT2) {
    const int col = blockIdx.x, k = threadIdx.x;
    if (col < 256) BT1[col * 256 + k] = (ushort_t)f2bf(Whd[(col >> 6) * 16384 + k * 64 + (col & 63)]);
    else           BT2[(col - 256) * 256 + k] = (ushort_t)f2bf(Wo[k * 64 + (col - 256)]);
}

// ---------------------------------------------------------------------------
// Fused MFMA GEMM: computes C-tile (never stored as f32), then in epilogue:
//  (a) s1/s2 scores via in-register shfl reduction (head = 64-col tile)
//  (b) bf16 transposed WhbT[b][f][j] via LDS bounce.
// A_BF16=0: A f32 (x); A_BF16=1: A bf16 (hcat). K=256 both layers.
// ---------------------------------------------------------------------------
template <int A_BF16>
__global__ __launch_bounds__(256, 4) void gemm_fused(
    const void* __restrict__ Ap, const ushort_t* __restrict__ BT,
    const float* __restrict__ av, ushort_t* __restrict__ WhbT,
    float* __restrict__ s1, float* __restrict__ s2, const int S) {
    constexpr int K = 256;
    __shared__ __align__(16) short tbuf[64][72];   // [f][j] bf16, stride 72 for 16B-aligned rows
    const int tid = threadIdx.x;
    const int w = tid >> 6, l = tid & 63, lo = l & 15, kg = l >> 4;
    const int row0 = blockIdx.y * 64, col0 = blockIdx.x * 64;
    const int b = row0 >> 10, j0 = row0 & (NN - 1);
    const int hsel = col0 >> 6;

    f32x4 acc[4];
    #pragma unroll
    for (int cb = 0; cb < 4; ++cb) acc[cb] = (f32x4){0.f, 0.f, 0.f, 0.f};

    if (A_BF16) {
        const ushort_t* __restrict__ arow = (const ushort_t*)Ap + (size_t)(row0 + w * 16 + lo) * K;
        #pragma unroll
        for (int ks = 0; ks < 8; ++ks) {
            const int k0 = ks * 32 + kg * 8;
            const short8 af = *(const short8*)(arow + k0);
            #pragma unroll
            for (int cb = 0; cb < 4; ++cb) {
                const short8 bf = *(const short8*)(BT + (size_t)(col0 + cb * 16 + lo) * K + k0);
                acc[cb] = __builtin_amdgcn_mfma_f32_16x16x32_bf16(af, bf, acc[cb], 0, 0, 0);
            }
        }
    } else {
        const float* __restrict__ arow = (const float*)Ap + (size_t)(row0 + w * 16 + lo) * K;
        #pragma unroll
        for (int ks = 0; ks < 8; ++ks) {
            const int k0 = ks * 32 + kg * 8;
            const float4 a0 = *(const float4*)(arow + k0);
            const float4 a1 = *(const float4*)(arow + k0 + 4);
            short8 af;
            af[0] = (short)f2bf(a0.x); af[1] = (short)f2bf(a0.y);
            af[2] = (short)f2bf(a0.z); af[3] = (short)f2bf(a0.w);
            af[4] = (short)f2bf(a1.x); af[5] = (short)f2bf(a1.y);
            af[6] = (short)f2bf(a1.z); af[7] = (short)f2bf(a1.w);
            #pragma unroll
            for (int cb = 0; cb < 4; ++cb) {
                const short8 bf = *(const short8*)(BT + (size_t)(col0 + cb * 16 + lo) * K + k0);
                acc[cb] = __builtin_amdgcn_mfma_f32_16x16x32_bf16(af, bf, acc[cb], 0, 0, 0);
            }
        }
    }

    // (a) scores: row R = row0+w*16+kg*4+r holds cols cb*16+lo in acc[cb][r]
    float a1v[4], a2v[4];
    #pragma unroll
    for (int cb = 0; cb < 4; ++cb) {
        a1v[cb] = av[hsel * 128 + cb * 16 + lo];
        a2v[cb] = av[hsel * 128 + 64 + cb * 16 + lo];
    }
    float sp1[4], sp2[4];
    #pragma unroll
    for (int r = 0; r < 4; ++r) {
        sp1[r] = acc[0][r] * a1v[0] + acc[1][r] * a1v[1] + acc[2][r] * a1v[2] + acc[3][r] * a1v[3];
        sp2[r] = acc[0][r] * a2v[0] + acc[1][r] * a2v[1] + acc[2][r] * a2v[2] + acc[3][r] * a2v[3];
    }
    #pragma unroll
    for (int m = 1; m < 16; m <<= 1) {
        #pragma unroll
        for (int r = 0; r < 4; ++r) {
            sp1[r] += __shfl_xor(sp1[r], m);
            sp2[r] += __shfl_xor(sp2[r], m);
        }
    }
    if (lo == 0) {
        #pragma unroll
        for (int r = 0; r < 4; ++r) {
            const int R = row0 + w * 16 + kg * 4 + r;
            s1[hsel * (BB * NN) + R] = sp1[r];
            s2[hsel * (BB * NN) + R] = sp2[r];
        }
    }

    // (b) WhbT bounce: tbuf[f][j]
    #pragma unroll
    for (int cb = 0; cb < 4; ++cb)
        #pragma unroll
        for (int rp = 0; rp < 2; ++rp) {
            unsigned lobf = f2bf(acc[cb][rp * 2]);
            unsigned hibf = f2bf(acc[cb][rp * 2 + 1]);
            ((unsigned*)tbuf)[(cb * 16 + lo) * 36 + w * 8 + kg * 2 + rp] = lobf | (hibf << 16);
        }
    __syncthreads();
    const int fl = tid >> 2, ch = tid & 3;
    const short8 v0 = *(const short8*)((const short*)tbuf + fl * 72 + ch * 16);
    const short8 v1 = *(const short8*)((const short*)tbuf + fl * 72 + ch * 16 + 8);
    ushort_t* dst = WhbT + ((size_t)(b * S) + col0 + fl) * NN + j0 + ch * 16;
    *(short8*)dst = v0;
    *(short8*)(dst + 8) = v1;
}

// ---------------------------------------------------------------------------
// Softmax stats per row: cs = -(max*log2e + log2(sum(exp(e-max))))
// ---------------------------------------------------------------------------
template <int H>
__global__ void stats_kernel(const float* __restrict__ s1, const float* __restrict__ s2,
                             const u64* __restrict__ bm, float* __restrict__ cs) {
    const int row = blockIdx.x;          // b*N + i
    const int b = row >> 10;
    const int tid = threadIdx.x;
    __shared__ float red[4];
    const unsigned bits = (unsigned)(bm[row * 16 + (tid >> 4)] >> ((tid & 15) * 4)) & 0xF;
    #pragma unroll
    for (int h = 0; h < H; ++h) {
        const int hb = h * (BB * NN);
        const float s1i = s1[hb + row];
        const float4 s2v = *(const float4*)(s2 + hb + b * NN + tid * 4);
        float e0 = s1i + s2v.x; e0 = fmaxf(e0, 0.2f * e0); e0 = (bits & 1) ? e0 : NEGV;
        float e1 = s1i + s2v.y; e1 = fmaxf(e1, 0.2f * e1); e1 = (bits & 2) ? e1 : NEGV;
        float e2 = s1i + s2v.z; e2 = fmaxf(e2, 0.2f * e2); e2 = (bits & 4) ? e2 : NEGV;
        float e3 = s1i + s2v.w; e3 = fmaxf(e3, 0.2f * e3); e3 = (bits & 8) ? e3 : NEGV;
        float mx = fmaxf(fmaxf(e0, e1), fmaxf(e2, e3));
        #pragma unroll
        for (int m = 32; m >= 1; m >>= 1) mx = fmaxf(mx, __shfl_xor(mx, m));
        if ((tid & 63) == 0) red[tid >> 6] = mx;
        __syncthreads();
        mx = fmaxf(fmaxf(red[0], red[1]), fmaxf(red[2], red[3]));
        __syncthreads();
        float s = __builtin_amdgcn_exp2f((e0 - mx) * LOG2E)
                + __builtin_amdgcn_exp2f((e1 - mx) * LOG2E)
                + __builtin_amdgcn_exp2f((e2 - mx) * LOG2E)
                + __builtin_amdgcn_exp2f((e3 - mx) * LOG2E);
        #pragma unroll
        for (int m = 32; m >= 1; m >>= 1) s += __shfl_xor(s, m);
        if ((tid & 63) == 0) red[tid >> 6] = s;
        __syncthreads();
        s = red[0] + red[1] + red[2] + red[3];
        if (tid == 0) cs[hb + row] = -(mx * LOG2E + __log2f(s));
        __syncthreads();
    }
}

// ---------------------------------------------------------------------------
// Fused attention apply: O^T = Wh^T . P^T via mfma. s2 + adj-bits staged in
// LDS; P = exp2(fma(e, log2e, c)) with masked e -> NEGV -> exp2 -> 0.
// H>1: z-dim = head (full j). JQ>1: z-dim = j-quarter (f32 partial out).
// XCD remap: the 16 i-tiles sharing one Wh panel land on one XCD.
// ---------------------------------------------------------------------------
template <int H, int JQ, int OUT_BF16>
__global__ __launch_bounds__(256, 4) void apply_kernel(
    const ushort_t* __restrict__ WhbT, const int S,
    const float* __restrict__ s1, const float* __restrict__ s2,
    const float* __restrict__ cs, const unsigned* __restrict__ bm32,
    void* __restrict__ outp) {
    constexpr int JLEN = NN / JQ;
    constexpr int BW = JLEN / 32;
    __shared__ __align__(16) float s2s[JLEN];
    __shared__ unsigned bs[64][BW + 1];
    __shared__ __align__(16) char obuf[OUT_BF16 ? (64 * 72 * 2) : (64 * 68 * 4)];

    const int Bk = blockIdx.x;
    const int lid = (Bk & 7) * 128 + (Bk >> 3);    // XCD-contiguous logical id
    const int it = lid & 15;
    const int b  = (lid >> 4) & 15;
    const int z  = lid >> 8;
    const int h  = (H > 1) ? z : 0;
    const int jq = (JQ > 1) ? z : 0;
    const int j0g = jq * JLEN;

    const int tid = threadIdx.x;
    const int w = tid >> 6, l = tid & 63;
    const int lo = l & 15, kg = l >> 4;
    const int iloc = w * 16 + lo;
    const int gi = b * NN + it * 64 + iloc;
    const int hb = h * (BB * NN);

    const float s1i = s1[hb + gi];
    const float cc  = cs[hb + gi];

    const float* __restrict__ s2g = s2 + hb + b * NN + j0g;
    for (int k = tid; k < JLEN / 4; k += 256)
        *(float4*)(s2s + k * 4) = *(const float4*)(s2g + k * 4);
    const int rbase = b * NN + it * 64;
    for (int idx = tid; idx < 64 * BW; idx += 256) {
        int r = idx / BW, wd = idx - r * BW;
        bs[r][wd] = bm32[(size_t)(rbase + r) * 32 + (j0g >> 5) + wd];
    }
    __syncthreads();

    const ushort_t* __restrict__ whb = WhbT + ((size_t)(b * S + h * FH)) * NN + j0g;

    f32x4 acc[4];
    #pragma unroll
    for (int fb = 0; fb < 4; ++fb) acc[fb] = (f32x4){0.f, 0.f, 0.f, 0.f};

    #pragma unroll 2
    for (int j = 0; j < JLEN; j += 32) {
        const int kb = j + kg * 8;
        const unsigned byte = (bs[iloc][j >> 5] >> (kg * 8)) & 0xFF;
        const float4 sa = *(const float4*)(s2s + kb);
        const float4 sb = *(const float4*)(s2s + kb + 4);
        const float s2r[8] = {sa.x, sa.y, sa.z, sa.w, sb.x, sb.y, sb.z, sb.w};
        short8 bfr;
        #pragma unroll
        for (int e = 0; e < 8; ++e) {
            float ev = s1i + s2r[e];
            ev = fmaxf(ev, 0.2f * ev);
            ev = ((byte >> e) & 1) ? ev : NEGV;
            bfr[e] = (short)f2bf(__builtin_amdgcn_exp2f(__builtin_fmaf(ev, LOG2E, cc)));
        }
        #pragma unroll
        for (int fb = 0; fb < 4; ++fb) {
            const short8 afr = *(const short8*)(whb + (size_t)(fb * 16 + lo) * NN + kb);
            acc[fb] = __builtin_amdgcn_mfma_f32_16x16x32_bf16(afr, bfr, acc[fb], 0, 0, 0);
        }
    }

    // lane (lo,kg) holds i = iloc, f = fb*16 + kg*4 + r
    if (OUT_BF16) {
        unsigned* ot = (unsigned*)obuf;                 // [64][36] u32 view of [64][72] bf16
        #pragma unroll
        for (int fb = 0; fb < 4; ++fb)
            #pragma unroll
            for (int rp = 0; rp < 2; ++rp) {
                unsigned lobf = f2bf(acc[fb][rp * 2]);
                unsigned hibf = f2bf(acc[fb][rp * 2 + 1]);
                ot[iloc * 36 + fb * 8 + kg * 2 + rp] = lobf | (hibf << 16);
            }
        __syncthreads();
        const int i2 = tid >> 2, ch = tid & 3;
        const short8 v0 = *(const short8*)((const short*)obuf + i2 * 72 + ch * 16);
        const short8 v1 = *(const short8*)((const short*)obuf + i2 * 72 + ch * 16 + 8);
        ushort_t* dst = (ushort_t*)outp + (size_t)(b * NN + it * 64 + i2) * 256 + h * FH + ch * 16;
        *(short8*)dst = v0;
        *(short8*)(dst + 8) = v1;
    } else {
        float* ot = (float*)obuf;                       // [64][68]
        #pragma unroll
        for (int fb = 0; fb < 4; ++fb)
            #pragma unroll
            for (int r = 0; r < 4; ++r)
                ot[iloc * 68 + fb * 16 + kg * 4 + r] = acc[fb][r];
        __syncthreads();
        const int i2 = tid >> 2, ch = tid & 3;
        const f32x4 u0 = *(const f32x4*)(ot + i2 * 68 + ch * 16);
        float* dst = (float*)outp + (size_t)jq * (BB * NN * FH)
                   + (size_t)(b * NN + it * 64 + i2) * FH + ch * 16;
        *(f32x4*)dst = u0;
        *(f32x4*)(dst + 4)  = *(const f32x4*)(ot + i2 * 68 + ch * 16 + 4);
        *(f32x4*)(dst + 8)  = *(const f32x4*)(ot + i2 * 68 + ch * 16 + 8);
        *(f32x4*)(dst + 12) = *(const f32x4*)(ot + i2 * 68 + ch * 16 + 12);
    }
}

// ---------------------------------------------------------------------------
// Combine 4 j-partials + ELU + mean over nodes.
// ---------------------------------------------------------------------------
__global__ __launch_bounds__(1024) void mean_kernel(const float* __restrict__ part,
                                                    float* __restrict__ out) {
    const int b = blockIdx.x;
    const int f = threadIdx.x & 63, g = threadIdx.x >> 6;   // g in 0..15
    float acc = 0.f;
    for (int i = g; i < NN; i += 16) {
        const size_t base = ((size_t)(b * NN + i)) * FH + f;
        float v = part[base] + part[base + 1048576] + part[base + 2097152] + part[base + 3145728];
        v = (v > 0.f) ? v : (__builtin_amdgcn_exp2f(v * LOG2E) - 1.0f);
        acc += v;
    }
    __shared__ float r[16][64];
    r[g][f] = acc;
    __syncthreads();
    if (g == 0) {
        float s = 0.f;
        #pragma unroll
        for (int q = 0; q < 16; ++q) s += r[q][f];
        out[b * FH + f] = s * (1.0f / NN);
    }
}

extern "C" void kernel_launch(void* const* d_in, const int* in_sizes, int n_in,
                              void* d_out, int out_size, void* d_ws, size_t ws_size,
                              hipStream_t stream) {
    const float* x       = (const float*)d_in[0];
    const int*   adj     = (const int*)d_in[1];
    const float* W_heads = (const float*)d_in[2];
    const float* a_heads = (const float*)d_in[3];
    const float* W_out   = (const float*)d_in[4];
    const float* a_out   = (const float*)d_in[5];
    float* out = (float*)d_out;
    float* f0  = (float*)d_ws;

    // workspace (float offsets). part(16MB) overlays hcat+WhbT1 (both dead).
    ushort_t* hcat  = (ushort_t*)f0;                     // [16384][256] bf16, 8 MB
    ushort_t* WhbT1 = (ushort_t*)(f0 + 2097152);         // [16][256][1024] bf16, 8 MB
    float*    part  = f0;                                // [4][16384][64] f32, 16 MB (after gemm2)
    ushort_t* WhbT2 = (ushort_t*)(f0 + 4194304);         // [16][64][1024] bf16, 2 MB
    u64*      bmask = (u64*)(f0 + 4718592);              // [16384][16] u64, 2 MB
    ushort_t* WbT1  = (ushort_t*)(f0 + 5242880);         // [256][256] bf16
    ushort_t* WbT2  = (ushort_t*)(f0 + 5275648);         // [64][256] bf16
    float*    s1_1  = f0 + 5283840;                      // [4][16384]
    float*    s2_1  = s1_1 + 65536;
    float*    cs_1  = s2_1 + 65536;
    float*    s1_2  = cs_1 + 65536;                      // [16384]
    float*    s2_2  = s1_2 + 16384;
    float*    cs_2  = s2_2 + 16384;

    dim3 blk(256);

    // shared pre-passes
    pack_kernel<<<dim3(BB * NN / 4), blk, 0, stream>>>(adj, bmask);
    packw_kernel<<<dim3(320), blk, 0, stream>>>(W_heads, W_out, WbT1, WbT2);

    // layer 1
    gemm_fused<0><<<dim3(4, 256), blk, 0, stream>>>(x, WbT1, a_heads, WhbT1, s1_1, s2_1, 256);
    stats_kernel<NH><<<dim3(BB * NN), blk, 0, stream>>>(s1_1, s2_1, bmask, cs_1);
    apply_kernel<NH, 1, 1><<<dim3(1024), blk, 0, stream>>>(WhbT1, 256, s1_1, s2_1, cs_1,
                                                           (const unsigned*)bmask, hcat);

    // layer 2
    gemm_fused<1><<<dim3(1, 256), blk, 0, stream>>>(hcat, WbT2, a_out, WhbT2, s1_2, s2_2, 64);
    stats_kernel<1><<<dim3(BB * NN), blk, 0, stream>>>(s1_2, s2_2, bmask, cs_2);
    apply_kernel<1, 4, 0><<<dim3(1024), blk, 0, stream>>>(WhbT2, 64, s1_2, s2_2, cs_2,
                                                          (const unsigned*)bmask, part);

    // combine partials + elu + mean
    mean_kernel<<<dim3(BB), dim3(1024), 0, stream>>>(part, out);
}

// Round 6
// 180.334 us; speedup vs baseline: 4.8136x; 1.2241x over previous
//
#include <hip/hip_runtime.h>
#include <math.h>

#define BB 16
#define NN 1024
#define FH 64
#define NH 4
#define NEGV -9.0e15f
#define LOG2E 1.4426950408889634f

typedef __attribute__((ext_vector_type(8))) short short8;
typedef __attribute__((ext_vector_type(4))) float f32x4;
typedef unsigned long long u64;
typedef unsigned short ushort_t;

__device__ inline unsigned f2bf(float x) {
    unsigned u = __builtin_bit_cast(unsigned, x);
    u += 0x7fff + ((u >> 16) & 1);   // round-to-nearest-even
    return u >> 16;
}

// ---------------------------------------------------------------------------
// adj -> bitmask. bm[row][g] bit l = adj[row*1024 + g*64 + l] > 0.
// ---------------------------------------------------------------------------
__global__ void pack_kernel(const int* __restrict__ adj, u64* __restrict__ bm) {
    const int row = blockIdx.x * 4 + (threadIdx.x >> 6);
    const int lane = threadIdx.x & 63;
    const int* __restrict__ ar = adj + (size_t)row * NN;
    #pragma unroll
    for (int g = 0; g < 16; ++g) {
        u64 m = __ballot(ar[g * 64 + lane] > 0);
        if (lane == 0) bm[row * 16 + g] = m;
    }
}

// ---------------------------------------------------------------------------
// Pack weights transposed to bf16: BT[col][k].
// ---------------------------------------------------------------------------
__global__ void packw_kernel(const float* __restrict__ Whd, const float* __restrict__ Wo,
                             ushort_t* __restrict__ BT1, ushort_t* __restrict__ BT2) {
    const int col = blockIdx.x, k = threadIdx.x;
    if (col < 256) BT1[col * 256 + k] = (ushort_t)f2bf(Whd[(col >> 6) * 16384 + k * 64 + (col & 63)]);
    else           BT2[(col - 256) * 256 + k] = (ushort_t)f2bf(Wo[k * 64 + (col - 256)]);
}

// ---------------------------------------------------------------------------
// Fused MFMA GEMM + score epilogue + bf16 transposed WhbT output.
// ---------------------------------------------------------------------------
template <int A_BF16>
__global__ __launch_bounds__(256, 4) void gemm_fused(
    const void* __restrict__ Ap, const ushort_t* __restrict__ BT,
    const float* __restrict__ av, ushort_t* __restrict__ WhbT,
    float* __restrict__ s1, float* __restrict__ s2, const int S) {
    constexpr int K = 256;
    __shared__ __align__(16) short tbuf[64][72];
    const int tid = threadIdx.x;
    const int w = tid >> 6, l = tid & 63, lo = l & 15, kg = l >> 4;
    const int row0 = blockIdx.y * 64, col0 = blockIdx.x * 64;
    const int b = row0 >> 10, j0 = row0 & (NN - 1);
    const int hsel = col0 >> 6;

    f32x4 acc[4];
    #pragma unroll
    for (int cb = 0; cb < 4; ++cb) acc[cb] = (f32x4){0.f, 0.f, 0.f, 0.f};

    if (A_BF16) {
        const ushort_t* __restrict__ arow = (const ushort_t*)Ap + (size_t)(row0 + w * 16 + lo) * K;
        #pragma unroll
        for (int ks = 0; ks < 8; ++ks) {
            const int k0 = ks * 32 + kg * 8;
            const short8 af = *(const short8*)(arow + k0);
            #pragma unroll
            for (int cb = 0; cb < 4; ++cb) {
                const short8 bf = *(const short8*)(BT + (size_t)(col0 + cb * 16 + lo) * K + k0);
                acc[cb] = __builtin_amdgcn_mfma_f32_16x16x32_bf16(af, bf, acc[cb], 0, 0, 0);
            }
        }
    } else {
        const float* __restrict__ arow = (const float*)Ap + (size_t)(row0 + w * 16 + lo) * K;
        #pragma unroll
        for (int ks = 0; ks < 8; ++ks) {
            const int k0 = ks * 32 + kg * 8;
            const float4 a0 = *(const float4*)(arow + k0);
            const float4 a1 = *(const float4*)(arow + k0 + 4);
            short8 af;
            af[0] = (short)f2bf(a0.x); af[1] = (short)f2bf(a0.y);
            af[2] = (short)f2bf(a0.z); af[3] = (short)f2bf(a0.w);
            af[4] = (short)f2bf(a1.x); af[5] = (short)f2bf(a1.y);
            af[6] = (short)f2bf(a1.z); af[7] = (short)f2bf(a1.w);
            #pragma unroll
            for (int cb = 0; cb < 4; ++cb) {
                const short8 bf = *(const short8*)(BT + (size_t)(col0 + cb * 16 + lo) * K + k0);
                acc[cb] = __builtin_amdgcn_mfma_f32_16x16x32_bf16(af, bf, acc[cb], 0, 0, 0);
            }
        }
    }

    float a1v[4], a2v[4];
    #pragma unroll
    for (int cb = 0; cb < 4; ++cb) {
        a1v[cb] = av[hsel * 128 + cb * 16 + lo];
        a2v[cb] = av[hsel * 128 + 64 + cb * 16 + lo];
    }
    float sp1[4], sp2[4];
    #pragma unroll
    for (int r = 0; r < 4; ++r) {
        sp1[r] = acc[0][r] * a1v[0] + acc[1][r] * a1v[1] + acc[2][r] * a1v[2] + acc[3][r] * a1v[3];
        sp2[r] = acc[0][r] * a2v[0] + acc[1][r] * a2v[1] + acc[2][r] * a2v[2] + acc[3][r] * a2v[3];
    }
    #pragma unroll
    for (int m = 1; m < 16; m <<= 1) {
        #pragma unroll
        for (int r = 0; r < 4; ++r) {
            sp1[r] += __shfl_xor(sp1[r], m);
            sp2[r] += __shfl_xor(sp2[r], m);
        }
    }
    if (lo == 0) {
        #pragma unroll
        for (int r = 0; r < 4; ++r) {
            const int R = row0 + w * 16 + kg * 4 + r;
            s1[hsel * (BB * NN) + R] = sp1[r];
            s2[hsel * (BB * NN) + R] = sp2[r];
        }
    }

    #pragma unroll
    for (int cb = 0; cb < 4; ++cb)
        #pragma unroll
        for (int rp = 0; rp < 2; ++rp) {
            unsigned lobf = f2bf(acc[cb][rp * 2]);
            unsigned hibf = f2bf(acc[cb][rp * 2 + 1]);
            ((unsigned*)tbuf)[(cb * 16 + lo) * 36 + w * 8 + kg * 2 + rp] = lobf | (hibf << 16);
        }
    __syncthreads();
    const int fl = tid >> 2, ch = tid & 3;
    const short8 v0 = *(const short8*)((const short*)tbuf + fl * 72 + ch * 16);
    const short8 v1 = *(const short8*)((const short*)tbuf + fl * 72 + ch * 16 + 8);
    ushort_t* dst = WhbT + ((size_t)(b * S) + col0 + fl) * NN + j0 + ch * 16;
    *(short8*)dst = v0;
    *(short8*)(dst + 8) = v1;
}

// ---------------------------------------------------------------------------
// Softmax stats per row: cs = -(max*log2e + log2(sum(exp(e-max))))
// ---------------------------------------------------------------------------
template <int H>
__global__ void stats_kernel(const float* __restrict__ s1, const float* __restrict__ s2,
                             const u64* __restrict__ bm, float* __restrict__ cs) {
    const int row = blockIdx.x;
    const int b = row >> 10;
    const int tid = threadIdx.x;
    __shared__ float red[4];
    const unsigned bits = (unsigned)(bm[row * 16 + (tid >> 4)] >> ((tid & 15) * 4)) & 0xF;
    #pragma unroll
    for (int h = 0; h < H; ++h) {
        const int hb = h * (BB * NN);
        const float s1i = s1[hb + row];
        const float4 s2v = *(const float4*)(s2 + hb + b * NN + tid * 4);
        float e0 = s1i + s2v.x; e0 = fmaxf(e0, 0.2f * e0); e0 = (bits & 1) ? e0 : NEGV;
        float e1 = s1i + s2v.y; e1 = fmaxf(e1, 0.2f * e1); e1 = (bits & 2) ? e1 : NEGV;
        float e2 = s1i + s2v.z; e2 = fmaxf(e2, 0.2f * e2); e2 = (bits & 4) ? e2 : NEGV;
        float e3 = s1i + s2v.w; e3 = fmaxf(e3, 0.2f * e3); e3 = (bits & 8) ? e3 : NEGV;
        float mx = fmaxf(fmaxf(e0, e1), fmaxf(e2, e3));
        #pragma unroll
        for (int m = 32; m >= 1; m >>= 1) mx = fmaxf(mx, __shfl_xor(mx, m));
        if ((tid & 63) == 0) red[tid >> 6] = mx;
        __syncthreads();
        mx = fmaxf(fmaxf(red[0], red[1]), fmaxf(red[2], red[3]));
        __syncthreads();
        float s = __builtin_amdgcn_exp2f((e0 - mx) * LOG2E)
                + __builtin_amdgcn_exp2f((e1 - mx) * LOG2E)
                + __builtin_amdgcn_exp2f((e2 - mx) * LOG2E)
                + __builtin_amdgcn_exp2f((e3 - mx) * LOG2E);
        #pragma unroll
        for (int m = 32; m >= 1; m >>= 1) s += __shfl_xor(s, m);
        if ((tid & 63) == 0) red[tid >> 6] = s;
        __syncthreads();
        s = red[0] + red[1] + red[2] + red[3];
        if (tid == 0) cs[hb + row] = -(mx * LOG2E + __log2f(s));
        __syncthreads();
    }
}

// ---------------------------------------------------------------------------
// Fused attention apply. Wh^T chunks (64f x 64j bf16) staged in LDS via a
// SINGLE buffer with the race-free 2-phase pattern: regs->LDS, barrier,
// (issue next chunk's global loads), compute from LDS, barrier. Slot-XOR
// swizzle keeps ds_read_b128 at 2 lanes/bank (free). P generated on the fly.
// ---------------------------------------------------------------------------
template <int H, int JQ, int OUT_BF16>
__global__ __launch_bounds__(256, 4) void apply_kernel(
    const ushort_t* __restrict__ WhbT, const int S,
    const float* __restrict__ s1, const float* __restrict__ s2,
    const float* __restrict__ cs, const unsigned* __restrict__ bm32,
    void* __restrict__ outp) {
    constexpr int JLEN = NN / JQ;
    constexpr int BW = JLEN / 32;
    constexpr int NCH = JLEN / 64;
    constexpr int OB = OUT_BF16 ? (64 * 72 * 2) : (64 * 68 * 4);
    constexpr int UBUF = (8192 > OB) ? 8192 : OB;

    __shared__ __align__(16) float s2s[JLEN];
    __shared__ unsigned bs[64][BW + 1];
    __shared__ __align__(16) char ubuf[UBUF];
    auto stage = (unsigned (*)[32])ubuf;           // [64 f-rows][8 slots x 4 u32]

    const int Bk = blockIdx.x;
    const int lid = (Bk & 7) * 128 + (Bk >> 3);    // XCD-contiguous logical id
    const int it = lid & 15;
    const int b  = (lid >> 4) & 15;
    const int z  = lid >> 8;
    const int h  = (H > 1) ? z : 0;
    const int jq = (JQ > 1) ? z : 0;
    const int j0g = jq * JLEN;

    const int tid = threadIdx.x;
    const int w = tid >> 6, l = tid & 63;
    const int lo = l & 15, kg = l >> 4;
    const int iloc = w * 16 + lo;
    const int rbase = b * NN + it * 64;
    const int gi = rbase + iloc;
    const int hb = h * (BB * NN);

    const ushort_t* __restrict__ whb = WhbT + ((size_t)(b * S + h * FH)) * NN + j0g;

    // staging thread map: rows r0 and r0+32, 16B slot st (swizzled by row)
    const int r0 = tid >> 3, st = tid & 7;
    const int sw = (st ^ (r0 & 7)) * 4;            // same for r0+32: (r0+32)&7 == r0&7
    const size_t ga = (size_t)r0 * NN + st * 8;
    const size_t gb = (size_t)(r0 + 32) * NN + st * 8;

    // issue chunk-0 global loads (latency hidden under s2/bits staging)
    int4 cv0 = *(const int4*)(whb + ga);
    int4 cv1 = *(const int4*)(whb + gb);

    // stage s2 segment + adjacency bits
    const float* __restrict__ s2g = s2 + hb + b * NN + j0g;
    for (int k = tid; k < JLEN / 4; k += 256)
        *(float4*)(s2s + k * 4) = *(const float4*)(s2g + k * 4);
    for (int idx = tid; idx < 64 * BW; idx += 256) {
        int r = idx / BW, wd = idx - r * BW;
        bs[r][wd] = bm32[(size_t)(rbase + r) * 32 + (j0g >> 5) + wd];
    }

    const float s1i = s1[hb + gi];
    const float cc  = cs[hb + gi];

    f32x4 acc[4];
    #pragma unroll
    for (int fb = 0; fb < 4; ++fb) acc[fb] = (f32x4){0.f, 0.f, 0.f, 0.f};

    __syncthreads();   // s2s/bs ready (stage not yet written)

    for (int c = 0; c < NCH; ++c) {
        // phase 1: write current chunk into the single stage buffer
        *(int4*)&stage[r0][sw] = cv0;
        *(int4*)&stage[r0 + 32][sw] = cv1;
        __syncthreads();                           // stage ready for all waves
        // issue next chunk's global loads now; latency hides under compute
        if (c + 1 < NCH) {
            const ushort_t* src = whb + (c + 1) * 64;
            cv0 = *(const int4*)(src + ga);
            cv1 = *(const int4*)(src + gb);
        }
        // phase 2: compute from LDS
        #pragma unroll
        for (int ks = 0; ks < 2; ++ks) {
            const int kb = c * 64 + ks * 32 + kg * 8;
            const unsigned byte = (bs[iloc][c * 2 + ks] >> (kg * 8)) & 0xFF;
            const float4 sa = *(const float4*)(s2s + kb);
            const float4 sb = *(const float4*)(s2s + kb + 4);
            const float s2r[8] = {sa.x, sa.y, sa.z, sa.w, sb.x, sb.y, sb.z, sb.w};
            short8 bfr;
            #pragma unroll
            for (int e = 0; e < 8; ++e) {
                float ev = s1i + s2r[e];
                ev = fmaxf(ev, 0.2f * ev);
                ev = ((byte >> e) & 1) ? ev : NEGV;
                bfr[e] = (short)f2bf(__builtin_amdgcn_exp2f(__builtin_fmaf(ev, LOG2E, cc)));
            }
            #pragma unroll
            for (int fb = 0; fb < 4; ++fb) {
                const int row = fb * 16 + lo;
                const int slot = (ks * 4 + kg) ^ (row & 7);
                const short8 afr = *(const short8*)&stage[row][slot * 4];
                acc[fb] = __builtin_amdgcn_mfma_f32_16x16x32_bf16(afr, bfr, acc[fb], 0, 0, 0);
            }
        }
        __syncthreads();                           // all reads done before next write
    }

    // lane (lo,kg) holds i = iloc, f = fb*16 + kg*4 + r
    if constexpr (OUT_BF16) {
        unsigned* ot = (unsigned*)ubuf;                 // [64][36] u32 view of [64][72] bf16
        #pragma unroll
        for (int fb = 0; fb < 4; ++fb)
            #pragma unroll
            for (int rp = 0; rp < 2; ++rp) {
                unsigned lobf = f2bf(acc[fb][rp * 2]);
                unsigned hibf = f2bf(acc[fb][rp * 2 + 1]);
                ot[iloc * 36 + fb * 8 + kg * 2 + rp] = lobf | (hibf << 16);
            }
        __syncthreads();
        const int i2 = tid >> 2, ch = tid & 3;
        const short8 v0 = *(const short8*)((const short*)ubuf + i2 * 72 + ch * 16);
        const short8 v1 = *(const short8*)((const short*)ubuf + i2 * 72 + ch * 16 + 8);
        ushort_t* dst = (ushort_t*)outp + (size_t)(b * NN + it * 64 + i2) * 256 + h * FH + ch * 16;
        *(short8*)dst = v0;
        *(short8*)(dst + 8) = v1;
    } else {
        float* ot = (float*)ubuf;                       // [64][68]
        #pragma unroll
        for (int fb = 0; fb < 4; ++fb)
            #pragma unroll
            for (int r = 0; r < 4; ++r)
                ot[iloc * 68 + fb * 16 + kg * 4 + r] = acc[fb][r];
        __syncthreads();
        const int i2 = tid >> 2, ch = tid & 3;
        float* dst = (float*)outp + (size_t)jq * (BB * NN * FH)
                   + (size_t)(b * NN + it * 64 + i2) * FH + ch * 16;
        *(f32x4*)dst        = *(const f32x4*)(ot + i2 * 68 + ch * 16);
        *(f32x4*)(dst + 4)  = *(const f32x4*)(ot + i2 * 68 + ch * 16 + 4);
        *(f32x4*)(dst + 8)  = *(const f32x4*)(ot + i2 * 68 + ch * 16 + 8);
        *(f32x4*)(dst + 12) = *(const f32x4*)(ot + i2 * 68 + ch * 16 + 12);
    }
}

// ---------------------------------------------------------------------------
// Combine 4 j-partials + ELU + mean over nodes.
// ---------------------------------------------------------------------------
__global__ __launch_bounds__(1024) void mean_kernel(const float* __restrict__ part,
                                                    float* __restrict__ out) {
    const int b = blockIdx.x;
    const int f = threadIdx.x & 63, g = threadIdx.x >> 6;   // g in 0..15
    float acc = 0.f;
    for (int i = g; i < NN; i += 16) {
        const size_t base = ((size_t)(b * NN + i)) * FH + f;
        float v = part[base] + part[base + 1048576] + part[base + 2097152] + part[base + 3145728];
        v = (v > 0.f) ? v : (__builtin_amdgcn_exp2f(v * LOG2E) - 1.0f);
        acc += v;
    }
    __shared__ float r[16][64];
    r[g][f] = acc;
    __syncthreads();
    if (g == 0) {
        float s = 0.f;
        #pragma unroll
        for (int q = 0; q < 16; ++q) s += r[q][f];
        out[b * FH + f] = s * (1.0f / NN);
    }
}

extern "C" void kernel_launch(void* const* d_in, const int* in_sizes, int n_in,
                              void* d_out, int out_size, void* d_ws, size_t ws_size,
                              hipStream_t stream) {
    const float* x       = (const float*)d_in[0];
    const int*   adj     = (const int*)d_in[1];
    const float* W_heads = (const float*)d_in[2];
    const float* a_heads = (const float*)d_in[3];
    const float* W_out   = (const float*)d_in[4];
    const float* a_out   = (const float*)d_in[5];
    float* out = (float*)d_out;
    float* f0  = (float*)d_ws;

    // workspace (float offsets). part(16MB) overlays hcat+WhbT1 (both dead).
    ushort_t* hcat  = (ushort_t*)f0;                     // [16384][256] bf16, 8 MB
    ushort_t* WhbT1 = (ushort_t*)(f0 + 2097152);         // [16][256][1024] bf16, 8 MB
    float*    part  = f0;                                // [4][16384][64] f32, 16 MB (after gemm2)
    ushort_t* WhbT2 = (ushort_t*)(f0 + 4194304);         // [16][64][1024] bf16, 2 MB
    u64*      bmask = (u64*)(f0 + 4718592);              // [16384][16] u64, 2 MB
    ushort_t* WbT1  = (ushort_t*)(f0 + 5242880);         // [256][256] bf16
    ushort_t* WbT2  = (ushort_t*)(f0 + 5275648);         // [64][256] bf16
    float*    s1_1  = f0 + 5283840;                      // [4][16384]
    float*    s2_1  = s1_1 + 65536;
    float*    cs_1  = s2_1 + 65536;
    float*    s1_2  = cs_1 + 65536;                      // [16384]
    float*    s2_2  = s1_2 + 16384;
    float*    cs_2  = s2_2 + 16384;

    dim3 blk(256);

    // shared pre-passes
    pack_kernel<<<dim3(BB * NN / 4), blk, 0, stream>>>(adj, bmask);
    packw_kernel<<<dim3(320), blk, 0, stream>>>(W_heads, W_out, WbT1, WbT2);

    // layer 1
    gemm_fused<0><<<dim3(4, 256), blk, 0, stream>>>(x, WbT1, a_heads, WhbT1, s1_1, s2_1, 256);
    stats_kernel<NH><<<dim3(BB * NN), blk, 0, stream>>>(s1_1, s2_1, bmask, cs_1);
    apply_kernel<NH, 1, 1><<<dim3(1024), blk, 0, stream>>>(WhbT1, 256, s1_1, s2_1, cs_1,
                                                           (const unsigned*)bmask, hcat);

    // layer 2
    gemm_fused<1><<<dim3(1, 256), blk, 0, stream>>>(hcat, WbT2, a_out, WhbT2, s1_2, s2_2, 64);
    stats_kernel<1><<<dim3(BB * NN), blk, 0, stream>>>(s1_2, s2_2, bmask, cs_2);
    apply_kernel<1, 4, 0><<<dim3(1024), blk, 0, stream>>>(WhbT2, 64, s1_2, s2_2, cs_2,
                                                          (const unsigned*)bmask, part);

    // combine partials + elu + mean
    mean_kernel<<<dim3(BB), dim3(1024), 0, stream>>>(part, out);
}

// Round 7
// 148.181 us; speedup vs baseline: 5.8581x; 1.2170x over previous
//
#include <hip/hip_runtime.h>
#include <math.h>

#define BB 16
#define NN 1024
#define FH 64
#define NH 4
#define NEGV -9.0e15f
#define LOG2E 1.4426950408889634f

typedef __attribute__((ext_vector_type(8))) short short8;
typedef __attribute__((ext_vector_type(4))) float f32x4;
typedef unsigned long long u64;
typedef unsigned short ushort_t;

__device__ inline unsigned f2bf(float x) {
    unsigned u = __builtin_bit_cast(unsigned, x);
    u += 0x7fff + ((u >> 16) & 1);   // round-to-nearest-even
    return u >> 16;
}

// ---------------------------------------------------------------------------
// adj -> bitmask. bm[row][g] bit l = adj[row*1024 + g*64 + l] > 0.
// ---------------------------------------------------------------------------
__global__ void pack_kernel(const int* __restrict__ adj, u64* __restrict__ bm) {
    const int row = blockIdx.x * 4 + (threadIdx.x >> 6);
    const int lane = threadIdx.x & 63;
    const int* __restrict__ ar = adj + (size_t)row * NN;
    #pragma unroll
    for (int g = 0; g < 16; ++g) {
        u64 m = __ballot(ar[g * 64 + lane] > 0);
        if (lane == 0) bm[row * 16 + g] = m;
    }
}

// ---------------------------------------------------------------------------
// Pack weights transposed to bf16: BT[col][k].
// ---------------------------------------------------------------------------
__global__ void packw_kernel(const float* __restrict__ Whd, const float* __restrict__ Wo,
                             ushort_t* __restrict__ BT1, ushort_t* __restrict__ BT2) {
    const int col = blockIdx.x, k = threadIdx.x;
    if (col < 256) BT1[col * 256 + k] = (ushort_t)f2bf(Whd[(col >> 6) * 16384 + k * 64 + (col & 63)]);
    else           BT2[(col - 256) * 256 + k] = (ushort_t)f2bf(Wo[k * 64 + (col - 256)]);
}

// ---------------------------------------------------------------------------
// Fused MFMA GEMM + score epilogue + bf16 transposed WhbT output.
// ---------------------------------------------------------------------------
template <int A_BF16>
__global__ __launch_bounds__(256, 4) void gemm_fused(
    const void* __restrict__ Ap, const ushort_t* __restrict__ BT,
    const float* __restrict__ av, ushort_t* __restrict__ WhbT,
    float* __restrict__ s1, float* __restrict__ s2, const int S) {
    constexpr int K = 256;
    __shared__ __align__(16) short tbuf[64][72];
    const int tid = threadIdx.x;
    const int w = tid >> 6, l = tid & 63, lo = l & 15, kg = l >> 4;
    const int row0 = blockIdx.y * 64, col0 = blockIdx.x * 64;
    const int b = row0 >> 10, j0 = row0 & (NN - 1);
    const int hsel = col0 >> 6;

    f32x4 acc[4];
    #pragma unroll
    for (int cb = 0; cb < 4; ++cb) acc[cb] = (f32x4){0.f, 0.f, 0.f, 0.f};

    if (A_BF16) {
        const ushort_t* __restrict__ arow = (const ushort_t*)Ap + (size_t)(row0 + w * 16 + lo) * K;
        #pragma unroll
        for (int ks = 0; ks < 8; ++ks) {
            const int k0 = ks * 32 + kg * 8;
            const short8 af = *(const short8*)(arow + k0);
            #pragma unroll
            for (int cb = 0; cb < 4; ++cb) {
                const short8 bf = *(const short8*)(BT + (size_t)(col0 + cb * 16 + lo) * K + k0);
                acc[cb] = __builtin_amdgcn_mfma_f32_16x16x32_bf16(af, bf, acc[cb], 0, 0, 0);
            }
        }
    } else {
        const float* __restrict__ arow = (const float*)Ap + (size_t)(row0 + w * 16 + lo) * K;
        #pragma unroll
        for (int ks = 0; ks < 8; ++ks) {
            const int k0 = ks * 32 + kg * 8;
            const float4 a0 = *(const float4*)(arow + k0);
            const float4 a1 = *(const float4*)(arow + k0 + 4);
            short8 af;
            af[0] = (short)f2bf(a0.x); af[1] = (short)f2bf(a0.y);
            af[2] = (short)f2bf(a0.z); af[3] = (short)f2bf(a0.w);
            af[4] = (short)f2bf(a1.x); af[5] = (short)f2bf(a1.y);
            af[6] = (short)f2bf(a1.z); af[7] = (short)f2bf(a1.w);
            #pragma unroll
            for (int cb = 0; cb < 4; ++cb) {
                const short8 bf = *(const short8*)(BT + (size_t)(col0 + cb * 16 + lo) * K + k0);
                acc[cb] = __builtin_amdgcn_mfma_f32_16x16x32_bf16(af, bf, acc[cb], 0, 0, 0);
            }
        }
    }

    float a1v[4], a2v[4];
    #pragma unroll
    for (int cb = 0; cb < 4; ++cb) {
        a1v[cb] = av[hsel * 128 + cb * 16 + lo];
        a2v[cb] = av[hsel * 128 + 64 + cb * 16 + lo];
    }
    float sp1[4], sp2[4];
    #pragma unroll
    for (int r = 0; r < 4; ++r) {
        sp1[r] = acc[0][r] * a1v[0] + acc[1][r] * a1v[1] + acc[2][r] * a1v[2] + acc[3][r] * a1v[3];
        sp2[r] = acc[0][r] * a2v[0] + acc[1][r] * a2v[1] + acc[2][r] * a2v[2] + acc[3][r] * a2v[3];
    }
    #pragma unroll
    for (int m = 1; m < 16; m <<= 1) {
        #pragma unroll
        for (int r = 0; r < 4; ++r) {
            sp1[r] += __shfl_xor(sp1[r], m);
            sp2[r] += __shfl_xor(sp2[r], m);
        }
    }
    if (lo == 0) {
        #pragma unroll
        for (int r = 0; r < 4; ++r) {
            const int R = row0 + w * 16 + kg * 4 + r;
            s1[hsel * (BB * NN) + R] = sp1[r];
            s2[hsel * (BB * NN) + R] = sp2[r];
        }
    }

    #pragma unroll
    for (int cb = 0; cb < 4; ++cb)
        #pragma unroll
        for (int rp = 0; rp < 2; ++rp) {
            unsigned lobf = f2bf(acc[cb][rp * 2]);
            unsigned hibf = f2bf(acc[cb][rp * 2 + 1]);
            ((unsigned*)tbuf)[(cb * 16 + lo) * 36 + w * 8 + kg * 2 + rp] = lobf | (hibf << 16);
        }
    __syncthreads();
    const int fl = tid >> 2, ch = tid & 3;
    const short8 v0 = *(const short8*)((const short*)tbuf + fl * 72 + ch * 16);
    const short8 v1 = *(const short8*)((const short*)tbuf + fl * 72 + ch * 16 + 8);
    ushort_t* dst = WhbT + ((size_t)(b * S) + col0 + fl) * NN + j0 + ch * 16;
    *(short8*)dst = v0;
    *(short8*)(dst + 8) = v1;
}

// ---------------------------------------------------------------------------
// Softmax stats, 64 rows/block, thread-per-row serial scan over LDS-staged
// s2 + adj bits. grid = (B*N/64, H). cs = -(max*log2e + log2(sum exp)).
// ---------------------------------------------------------------------------
__global__ __launch_bounds__(256) void stats_kernel(
    const float* __restrict__ s1, const float* __restrict__ s2,
    const unsigned* __restrict__ bm32, float* __restrict__ cs) {
    const int rbase = blockIdx.x * 64;          // row base in B*N
    const int h = blockIdx.y;
    const int b = rbase >> 10;
    const int hb = h * (BB * NN);
    const int tid = threadIdx.x;

    __shared__ __align__(16) float s2s[NN];
    __shared__ unsigned bs[64][33];             // stride 33: 2-way bank access (free)
    __shared__ float red[2][4][64];

    *(float4*)(s2s + tid * 4) = *(const float4*)(s2 + hb + b * NN + tid * 4);
    #pragma unroll
    for (int idx = tid; idx < 2048; idx += 256)
        bs[idx >> 5][idx & 31] = bm32[(size_t)(rbase + (idx >> 5)) * 32 + (idx & 31)];
    __syncthreads();

    const int r = tid & 63, q = tid >> 6;       // row r, j-quarter q
    const float s1r = s1[hb + rbase + r];

    // pass 1: masked leaky-relu max over this quarter
    float mx = -INFINITY;
    for (int wd = 0; wd < 8; ++wd) {
        const unsigned u = bs[r][q * 8 + wd];
        const int jb = q * 256 + wd * 32;
        #pragma unroll
        for (int g2 = 0; g2 < 8; ++g2) {
            const float4 sv = *(const float4*)(s2s + jb + g2 * 4);
            const unsigned nb = (u >> (g2 * 4)) & 0xF;
            float e0 = s1r + sv.x; e0 = fmaxf(e0, 0.2f * e0); e0 = (nb & 1) ? e0 : NEGV;
            float e1 = s1r + sv.y; e1 = fmaxf(e1, 0.2f * e1); e1 = (nb & 2) ? e1 : NEGV;
            float e2 = s1r + sv.z; e2 = fmaxf(e2, 0.2f * e2); e2 = (nb & 4) ? e2 : NEGV;
            float e3 = s1r + sv.w; e3 = fmaxf(e3, 0.2f * e3); e3 = (nb & 8) ? e3 : NEGV;
            mx = fmaxf(mx, fmaxf(fmaxf(e0, e1), fmaxf(e2, e3)));
        }
    }
    red[0][q][r] = mx;
    __syncthreads();
    mx = fmaxf(fmaxf(red[0][0][r], red[0][1][r]), fmaxf(red[0][2][r], red[0][3][r]));
    const float nm = -mx * LOG2E;

    // pass 2: sum of exp2(e*log2e - mx*log2e); masked -> exp2(-huge) = 0
    float sm = 0.f;
    for (int wd = 0; wd < 8; ++wd) {
        const unsigned u = bs[r][q * 8 + wd];
        const int jb = q * 256 + wd * 32;
        #pragma unroll
        for (int g2 = 0; g2 < 8; ++g2) {
            const float4 sv = *(const float4*)(s2s + jb + g2 * 4);
            const unsigned nb = (u >> (g2 * 4)) & 0xF;
            float e0 = s1r + sv.x; e0 = fmaxf(e0, 0.2f * e0); e0 = (nb & 1) ? e0 : NEGV;
            float e1 = s1r + sv.y; e1 = fmaxf(e1, 0.2f * e1); e1 = (nb & 2) ? e1 : NEGV;
            float e2 = s1r + sv.z; e2 = fmaxf(e2, 0.2f * e2); e2 = (nb & 4) ? e2 : NEGV;
            float e3 = s1r + sv.w; e3 = fmaxf(e3, 0.2f * e3); e3 = (nb & 8) ? e3 : NEGV;
            sm += __builtin_amdgcn_exp2f(__builtin_fmaf(e0, LOG2E, nm))
                + __builtin_amdgcn_exp2f(__builtin_fmaf(e1, LOG2E, nm))
                + __builtin_amdgcn_exp2f(__builtin_fmaf(e2, LOG2E, nm))
                + __builtin_amdgcn_exp2f(__builtin_fmaf(e3, LOG2E, nm));
        }
    }
    red[1][q][r] = sm;
    __syncthreads();
    if (tid < 64) {
        const float s = red[1][0][tid] + red[1][1][tid] + red[1][2][tid] + red[1][3][tid];
        const float m2 = fmaxf(fmaxf(red[0][0][tid], red[0][1][tid]),
                               fmaxf(red[0][2][tid], red[0][3][tid]));
        cs[hb + rbase + tid] = -(m2 * LOG2E + __log2f(s));
    }
}

// ---------------------------------------------------------------------------
// Fused attention apply (unchanged from round 6).
// ---------------------------------------------------------------------------
template <int H, int JQ, int OUT_BF16>
__global__ __launch_bounds__(256, 4) void apply_kernel(
    const ushort_t* __restrict__ WhbT, const int S,
    const float* __restrict__ s1, const float* __restrict__ s2,
    const float* __restrict__ cs, const unsigned* __restrict__ bm32,
    void* __restrict__ outp) {
    constexpr int JLEN = NN / JQ;
    constexpr int BW = JLEN / 32;
    constexpr int NCH = JLEN / 64;
    constexpr int OB = OUT_BF16 ? (64 * 72 * 2) : (64 * 68 * 4);
    constexpr int UBUF = (8192 > OB) ? 8192 : OB;

    __shared__ __align__(16) float s2s[JLEN];
    __shared__ unsigned bs[64][BW + 1];
    __shared__ __align__(16) char ubuf[UBUF];
    auto stage = (unsigned (*)[32])ubuf;           // [64 f-rows][8 slots x 4 u32]

    const int Bk = blockIdx.x;
    const int lid = (Bk & 7) * 128 + (Bk >> 3);    // XCD-contiguous logical id
    const int it = lid & 15;
    const int b  = (lid >> 4) & 15;
    const int z  = lid >> 8;
    const int h  = (H > 1) ? z : 0;
    const int jq = (JQ > 1) ? z : 0;
    const int j0g = jq * JLEN;

    const int tid = threadIdx.x;
    const int w = tid >> 6, l = tid & 63;
    const int lo = l & 15, kg = l >> 4;
    const int iloc = w * 16 + lo;
    const int rbase = b * NN + it * 64;
    const int gi = rbase + iloc;
    const int hb = h * (BB * NN);

    const ushort_t* __restrict__ whb = WhbT + ((size_t)(b * S + h * FH)) * NN + j0g;

    const int r0 = tid >> 3, st = tid & 7;
    const int sw = (st ^ (r0 & 7)) * 4;
    const size_t ga = (size_t)r0 * NN + st * 8;
    const size_t gb = (size_t)(r0 + 32) * NN + st * 8;

    int4 cv0 = *(const int4*)(whb + ga);
    int4 cv1 = *(const int4*)(whb + gb);

    const float* __restrict__ s2g = s2 + hb + b * NN + j0g;
    for (int k = tid; k < JLEN / 4; k += 256)
        *(float4*)(s2s + k * 4) = *(const float4*)(s2g + k * 4);
    for (int idx = tid; idx < 64 * BW; idx += 256) {
        int r = idx / BW, wd = idx - r * BW;
        bs[r][wd] = bm32[(size_t)(rbase + r) * 32 + (j0g >> 5) + wd];
    }

    const float s1i = s1[hb + gi];
    const float cc  = cs[hb + gi];

    f32x4 acc[4];
    #pragma unroll
    for (int fb = 0; fb < 4; ++fb) acc[fb] = (f32x4){0.f, 0.f, 0.f, 0.f};

    __syncthreads();

    for (int c = 0; c < NCH; ++c) {
        *(int4*)&stage[r0][sw] = cv0;
        *(int4*)&stage[r0 + 32][sw] = cv1;
        __syncthreads();
        if (c + 1 < NCH) {
            const ushort_t* src = whb + (c + 1) * 64;
            cv0 = *(const int4*)(src + ga);
            cv1 = *(const int4*)(src + gb);
        }
        #pragma unroll
        for (int ks = 0; ks < 2; ++ks) {
            const int kb = c * 64 + ks * 32 + kg * 8;
            const unsigned byte = (bs[iloc][c * 2 + ks] >> (kg * 8)) & 0xFF;
            const float4 sa = *(const float4*)(s2s + kb);
            const float4 sb = *(const float4*)(s2s + kb + 4);
            const float s2r[8] = {sa.x, sa.y, sa.z, sa.w, sb.x, sb.y, sb.z, sb.w};
            short8 bfr;
            #pragma unroll
            for (int e = 0; e < 8; ++e) {
                float ev = s1i + s2r[e];
                ev = fmaxf(ev, 0.2f * ev);
                ev = ((byte >> e) & 1) ? ev : NEGV;
                bfr[e] = (short)f2bf(__builtin_amdgcn_exp2f(__builtin_fmaf(ev, LOG2E, cc)));
            }
            #pragma unroll
            for (int fb = 0; fb < 4; ++fb) {
                const int row = fb * 16 + lo;
                const int slot = (ks * 4 + kg) ^ (row & 7);
                const short8 afr = *(const short8*)&stage[row][slot * 4];
                acc[fb] = __builtin_amdgcn_mfma_f32_16x16x32_bf16(afr, bfr, acc[fb], 0, 0, 0);
            }
        }
        __syncthreads();
    }

    if constexpr (OUT_BF16) {
        unsigned* ot = (unsigned*)ubuf;
        #pragma unroll
        for (int fb = 0; fb < 4; ++fb)
            #pragma unroll
            for (int rp = 0; rp < 2; ++rp) {
                unsigned lobf = f2bf(acc[fb][rp * 2]);
                unsigned hibf = f2bf(acc[fb][rp * 2 + 1]);
                ot[iloc * 36 + fb * 8 + kg * 2 + rp] = lobf | (hibf << 16);
            }
        __syncthreads();
        const int i2 = tid >> 2, ch = tid & 3;
        const short8 v0 = *(const short8*)((const short*)ubuf + i2 * 72 + ch * 16);
        const short8 v1 = *(const short8*)((const short*)ubuf + i2 * 72 + ch * 16 + 8);
        ushort_t* dst = (ushort_t*)outp + (size_t)(b * NN + it * 64 + i2) * 256 + h * FH + ch * 16;
        *(short8*)dst = v0;
        *(short8*)(dst + 8) = v1;
    } else {
        float* ot = (float*)ubuf;
        #pragma unroll
        for (int fb = 0; fb < 4; ++fb)
            #pragma unroll
            for (int r = 0; r < 4; ++r)
                ot[iloc * 68 + fb * 16 + kg * 4 + r] = acc[fb][r];
        __syncthreads();
        const int i2 = tid >> 2, ch = tid & 3;
        float* dst = (float*)outp + (size_t)jq * (BB * NN * FH)
                   + (size_t)(b * NN + it * 64 + i2) * FH + ch * 16;
        *(f32x4*)dst        = *(const f32x4*)(ot + i2 * 68 + ch * 16);
        *(f32x4*)(dst + 4)  = *(const f32x4*)(ot + i2 * 68 + ch * 16 + 4);
        *(f32x4*)(dst + 8)  = *(const f32x4*)(ot + i2 * 68 + ch * 16 + 8);
        *(f32x4*)(dst + 12) = *(const f32x4*)(ot + i2 * 68 + ch * 16 + 12);
    }
}

// ---------------------------------------------------------------------------
// Mean stage 1: 256 blocks (b, 64-row chunk) -> partial sums (with ELU).
// ---------------------------------------------------------------------------
__global__ __launch_bounds__(256) void mean1_kernel(const float* __restrict__ part,
                                                    float* __restrict__ partial) {
    const int b = blockIdx.x, ck = blockIdx.y;
    const int tid = threadIdx.x;
    const int f = tid & 63, g = tid >> 6;
    float acc = 0.f;
    #pragma unroll
    for (int i = g; i < 64; i += 4) {
        const size_t base = ((size_t)(b * NN + ck * 64 + i)) * FH + f;
        float v = part[base] + part[base + 1048576] + part[base + 2097152] + part[base + 3145728];
        v = (v > 0.f) ? v : (__builtin_amdgcn_exp2f(v * LOG2E) - 1.0f);
        acc += v;
    }
    __shared__ float r[4][64];
    r[g][f] = acc;
    __syncthreads();
    if (g == 0)
        partial[(b * 16 + ck) * FH + f] = r[0][f] + r[1][f] + r[2][f] + r[3][f];
}

// ---------------------------------------------------------------------------
// Mean stage 2: one block combines 16 chunk-partials per (b,f).
// ---------------------------------------------------------------------------
__global__ __launch_bounds__(1024) void mean2_kernel(const float* __restrict__ partial,
                                                     float* __restrict__ out) {
    const int t = threadIdx.x;          // 1024 = 16 b x 64 f
    const int b = t >> 6, f = t & 63;
    float s = 0.f;
    #pragma unroll
    for (int ck = 0; ck < 16; ++ck) s += partial[(b * 16 + ck) * FH + f];
    out[b * FH + f] = s * (1.0f / NN);
}

extern "C" void kernel_launch(void* const* d_in, const int* in_sizes, int n_in,
                              void* d_out, int out_size, void* d_ws, size_t ws_size,
                              hipStream_t stream) {
    const float* x       = (const float*)d_in[0];
    const int*   adj     = (const int*)d_in[1];
    const float* W_heads = (const float*)d_in[2];
    const float* a_heads = (const float*)d_in[3];
    const float* W_out   = (const float*)d_in[4];
    const float* a_out   = (const float*)d_in[5];
    float* out = (float*)d_out;
    float* f0  = (float*)d_ws;

    // workspace (float offsets). part(16MB) overlays hcat+WhbT1 (both dead).
    ushort_t* hcat  = (ushort_t*)f0;                     // [16384][256] bf16, 8 MB
    ushort_t* WhbT1 = (ushort_t*)(f0 + 2097152);         // [16][256][1024] bf16, 8 MB
    float*    part  = f0;                                // [4][16384][64] f32, 16 MB (after gemm2)
    ushort_t* WhbT2 = (ushort_t*)(f0 + 4194304);         // [16][64][1024] bf16, 2 MB
    u64*      bmask = (u64*)(f0 + 4718592);              // [16384][16] u64, 2 MB
    ushort_t* WbT1  = (ushort_t*)(f0 + 5242880);         // [256][256] bf16
    ushort_t* WbT2  = (ushort_t*)(f0 + 5275648);         // [64][256] bf16
    float*    s1_1  = f0 + 5283840;                      // [4][16384]
    float*    s2_1  = s1_1 + 65536;
    float*    cs_1  = s2_1 + 65536;
    float*    s1_2  = cs_1 + 65536;                      // [16384]
    float*    s2_2  = s1_2 + 16384;
    float*    cs_2  = s2_2 + 16384;
    float*    partial = cs_2 + 16384;                    // [16][16][64]

    dim3 blk(256);

    // shared pre-passes
    pack_kernel<<<dim3(BB * NN / 4), blk, 0, stream>>>(adj, bmask);
    packw_kernel<<<dim3(320), blk, 0, stream>>>(W_heads, W_out, WbT1, WbT2);

    // layer 1
    gemm_fused<0><<<dim3(4, 256), blk, 0, stream>>>(x, WbT1, a_heads, WhbT1, s1_1, s2_1, 256);
    stats_kernel<<<dim3(256, NH), blk, 0, stream>>>(s1_1, s2_1, (const unsigned*)bmask, cs_1);
    apply_kernel<NH, 1, 1><<<dim3(1024), blk, 0, stream>>>(WhbT1, 256, s1_1, s2_1, cs_1,
                                                           (const unsigned*)bmask, hcat);

    // layer 2
    gemm_fused<1><<<dim3(1, 256), blk, 0, stream>>>(hcat, WbT2, a_out, WhbT2, s1_2, s2_2, 64);
    stats_kernel<<<dim3(256, 1), blk, 0, stream>>>(s1_2, s2_2, (const unsigned*)bmask, cs_2);
    apply_kernel<1, 4, 0><<<dim3(1024), blk, 0, stream>>>(WhbT2, 64, s1_2, s2_2, cs_2,
                                                          (const unsigned*)bmask, part);

    // combine partials + elu + mean (two-stage)
    mean1_kernel<<<dim3(BB, 16), blk, 0, stream>>>(part, partial);
    mean2_kernel<<<dim3(1), dim3(1024), 0, stream>>>(partial, out);
}

// Round 8
// 147.959 us; speedup vs baseline: 5.8669x; 1.0015x over previous
//
#include <hip/hip_runtime.h>
#include <math.h>

#define BB 16
#define NN 1024
#define FH 64
#define NH 4
#define NEGV -9.0e15f
#define LOG2E 1.4426950408889634f

typedef __attribute__((ext_vector_type(8))) short short8;
typedef __attribute__((ext_vector_type(4))) float f32x4;
typedef unsigned long long u64;
typedef unsigned short ushort_t;

__device__ inline unsigned f2bf(float x) {
    unsigned u = __builtin_bit_cast(unsigned, x);
    u += 0x7fff + ((u >> 16) & 1);   // round-to-nearest-even
    return u >> 16;
}

// ---------------------------------------------------------------------------
// adj -> bitmask. bm[row][g] bit l = adj[row*1024 + g*64 + l] > 0.
// ---------------------------------------------------------------------------
__global__ void pack_kernel(const int* __restrict__ adj, u64* __restrict__ bm) {
    const int row = blockIdx.x * 4 + (threadIdx.x >> 6);
    const int lane = threadIdx.x & 63;
    const int* __restrict__ ar = adj + (size_t)row * NN;
    #pragma unroll
    for (int g = 0; g < 16; ++g) {
        u64 m = __ballot(ar[g * 64 + lane] > 0);
        if (lane == 0) bm[row * 16 + g] = m;
    }
}

// ---------------------------------------------------------------------------
// Pack weights transposed to bf16: BT[col][k].
// ---------------------------------------------------------------------------
__global__ void packw_kernel(const float* __restrict__ Whd, const float* __restrict__ Wo,
                             ushort_t* __restrict__ BT1, ushort_t* __restrict__ BT2) {
    const int col = blockIdx.x, k = threadIdx.x;
    if (col < 256) BT1[col * 256 + k] = (ushort_t)f2bf(Whd[(col >> 6) * 16384 + k * 64 + (col & 63)]);
    else           BT2[(col - 256) * 256 + k] = (ushort_t)f2bf(Wo[k * 64 + (col - 256)]);
}

// ---------------------------------------------------------------------------
// Fused MFMA GEMM + score epilogue + bf16 transposed WhbT output.
// XCD-swizzled block ids: the col-tiles sharing an A-row-panel -> same XCD L2.
// ---------------------------------------------------------------------------
template <int A_BF16>
__global__ __launch_bounds__(256, 4) void gemm_fused(
    const void* __restrict__ Ap, const ushort_t* __restrict__ BT,
    const float* __restrict__ av, ushort_t* __restrict__ WhbT,
    float* __restrict__ s1, float* __restrict__ s2, const int S) {
    constexpr int K = 256;
    __shared__ __align__(16) short tbuf[64][72];
    const int tid = threadIdx.x;
    const int w = tid >> 6, l = tid & 63, lo = l & 15, kg = l >> 4;

    const int nx = gridDim.x;
    const int id = blockIdx.y * nx + blockIdx.x;
    const int nwg = nx * gridDim.y;
    const int lid = (id & 7) * (nwg >> 3) + (id >> 3);   // bijective: nwg % 8 == 0
    const int row0 = (lid / nx) * 64, col0 = (lid % nx) * 64;

    const int b = row0 >> 10, j0 = row0 & (NN - 1);
    const int hsel = col0 >> 6;

    f32x4 acc[4];
    #pragma unroll
    for (int cb = 0; cb < 4; ++cb) acc[cb] = (f32x4){0.f, 0.f, 0.f, 0.f};

    if (A_BF16) {
        const ushort_t* __restrict__ arow = (const ushort_t*)Ap + (size_t)(row0 + w * 16 + lo) * K;
        #pragma unroll
        for (int ks = 0; ks < 8; ++ks) {
            const int k0 = ks * 32 + kg * 8;
            const short8 af = *(const short8*)(arow + k0);
            #pragma unroll
            for (int cb = 0; cb < 4; ++cb) {
                const short8 bf = *(const short8*)(BT + (size_t)(col0 + cb * 16 + lo) * K + k0);
                acc[cb] = __builtin_amdgcn_mfma_f32_16x16x32_bf16(af, bf, acc[cb], 0, 0, 0);
            }
        }
    } else {
        const float* __restrict__ arow = (const float*)Ap + (size_t)(row0 + w * 16 + lo) * K;
        #pragma unroll
        for (int ks = 0; ks < 8; ++ks) {
            const int k0 = ks * 32 + kg * 8;
            const float4 a0 = *(const float4*)(arow + k0);
            const float4 a1 = *(const float4*)(arow + k0 + 4);
            short8 af;
            af[0] = (short)f2bf(a0.x); af[1] = (short)f2bf(a0.y);
            af[2] = (short)f2bf(a0.z); af[3] = (short)f2bf(a0.w);
            af[4] = (short)f2bf(a1.x); af[5] = (short)f2bf(a1.y);
            af[6] = (short)f2bf(a1.z); af[7] = (short)f2bf(a1.w);
            #pragma unroll
            for (int cb = 0; cb < 4; ++cb) {
                const short8 bf = *(const short8*)(BT + (size_t)(col0 + cb * 16 + lo) * K + k0);
                acc[cb] = __builtin_amdgcn_mfma_f32_16x16x32_bf16(af, bf, acc[cb], 0, 0, 0);
            }
        }
    }

    float a1v[4], a2v[4];
    #pragma unroll
    for (int cb = 0; cb < 4; ++cb) {
        a1v[cb] = av[hsel * 128 + cb * 16 + lo];
        a2v[cb] = av[hsel * 128 + 64 + cb * 16 + lo];
    }
    float sp1[4], sp2[4];
    #pragma unroll
    for (int r = 0; r < 4; ++r) {
        sp1[r] = acc[0][r] * a1v[0] + acc[1][r] * a1v[1] + acc[2][r] * a1v[2] + acc[3][r] * a1v[3];
        sp2[r] = acc[0][r] * a2v[0] + acc[1][r] * a2v[1] + acc[2][r] * a2v[2] + acc[3][r] * a2v[3];
    }
    #pragma unroll
    for (int m = 1; m < 16; m <<= 1) {
        #pragma unroll
        for (int r = 0; r < 4; ++r) {
            sp1[r] += __shfl_xor(sp1[r], m);
            sp2[r] += __shfl_xor(sp2[r], m);
        }
    }
    if (lo == 0) {
        #pragma unroll
        for (int r = 0; r < 4; ++r) {
            const int R = row0 + w * 16 + kg * 4 + r;
            s1[hsel * (BB * NN) + R] = sp1[r];
            s2[hsel * (BB * NN) + R] = sp2[r];
        }
    }

    #pragma unroll
    for (int cb = 0; cb < 4; ++cb)
        #pragma unroll
        for (int rp = 0; rp < 2; ++rp) {
            unsigned lobf = f2bf(acc[cb][rp * 2]);
            unsigned hibf = f2bf(acc[cb][rp * 2 + 1]);
            ((unsigned*)tbuf)[(cb * 16 + lo) * 36 + w * 8 + kg * 2 + rp] = lobf | (hibf << 16);
        }
    __syncthreads();
    const int fl = tid >> 2, ch = tid & 3;
    const short8 v0 = *(const short8*)((const short*)tbuf + fl * 72 + ch * 16);
    const short8 v1 = *(const short8*)((const short*)tbuf + fl * 72 + ch * 16 + 8);
    ushort_t* dst = WhbT + ((size_t)(b * S) + col0 + fl) * NN + j0 + ch * 16;
    *(short8*)dst = v0;
    *(short8*)(dst + 8) = v1;
}

// ---------------------------------------------------------------------------
// Softmax stats, 64 rows/block, thread-per-row serial scan over LDS-staged
// s2 + adj bits. grid = (B*N/64, H). cs = -(max*log2e + log2(sum exp)).
// ---------------------------------------------------------------------------
__global__ __launch_bounds__(256) void stats_kernel(
    const float* __restrict__ s1, const float* __restrict__ s2,
    const unsigned* __restrict__ bm32, float* __restrict__ cs) {
    const int rbase = blockIdx.x * 64;
    const int h = blockIdx.y;
    const int b = rbase >> 10;
    const int hb = h * (BB * NN);
    const int tid = threadIdx.x;

    __shared__ __align__(16) float s2s[NN];
    __shared__ unsigned bs[64][33];
    __shared__ float red[2][4][64];

    *(float4*)(s2s + tid * 4) = *(const float4*)(s2 + hb + b * NN + tid * 4);
    #pragma unroll
    for (int idx = tid; idx < 2048; idx += 256)
        bs[idx >> 5][idx & 31] = bm32[(size_t)(rbase + (idx >> 5)) * 32 + (idx & 31)];
    __syncthreads();

    const int r = tid & 63, q = tid >> 6;
    const float s1r = s1[hb + rbase + r];

    float mx = -INFINITY;
    for (int wd = 0; wd < 8; ++wd) {
        const unsigned u = bs[r][q * 8 + wd];
        const int jb = q * 256 + wd * 32;
        #pragma unroll
        for (int g2 = 0; g2 < 8; ++g2) {
            const float4 sv = *(const float4*)(s2s + jb + g2 * 4);
            const unsigned nb = (u >> (g2 * 4)) & 0xF;
            float e0 = s1r + sv.x; e0 = fmaxf(e0, 0.2f * e0); e0 = (nb & 1) ? e0 : NEGV;
            float e1 = s1r + sv.y; e1 = fmaxf(e1, 0.2f * e1); e1 = (nb & 2) ? e1 : NEGV;
            float e2 = s1r + sv.z; e2 = fmaxf(e2, 0.2f * e2); e2 = (nb & 4) ? e2 : NEGV;
            float e3 = s1r + sv.w; e3 = fmaxf(e3, 0.2f * e3); e3 = (nb & 8) ? e3 : NEGV;
            mx = fmaxf(mx, fmaxf(fmaxf(e0, e1), fmaxf(e2, e3)));
        }
    }
    red[0][q][r] = mx;
    __syncthreads();
    mx = fmaxf(fmaxf(red[0][0][r], red[0][1][r]), fmaxf(red[0][2][r], red[0][3][r]));
    const float nm = -mx * LOG2E;

    float sm = 0.f;
    for (int wd = 0; wd < 8; ++wd) {
        const unsigned u = bs[r][q * 8 + wd];
        const int jb = q * 256 + wd * 32;
        #pragma unroll
        for (int g2 = 0; g2 < 8; ++g2) {
            const float4 sv = *(const float4*)(s2s + jb + g2 * 4);
            const unsigned nb = (u >> (g2 * 4)) & 0xF;
            float e0 = s1r + sv.x; e0 = fmaxf(e0, 0.2f * e0); e0 = (nb & 1) ? e0 : NEGV;
            float e1 = s1r + sv.y; e1 = fmaxf(e1, 0.2f * e1); e1 = (nb & 2) ? e1 : NEGV;
            float e2 = s1r + sv.z; e2 = fmaxf(e2, 0.2f * e2); e2 = (nb & 4) ? e2 : NEGV;
            float e3 = s1r + sv.w; e3 = fmaxf(e3, 0.2f * e3); e3 = (nb & 8) ? e3 : NEGV;
            sm += __builtin_amdgcn_exp2f(__builtin_fmaf(e0, LOG2E, nm))
                + __builtin_amdgcn_exp2f(__builtin_fmaf(e1, LOG2E, nm))
                + __builtin_amdgcn_exp2f(__builtin_fmaf(e2, LOG2E, nm))
                + __builtin_amdgcn_exp2f(__builtin_fmaf(e3, LOG2E, nm));
        }
    }
    red[1][q][r] = sm;
    __syncthreads();
    if (tid < 64) {
        const float s = red[1][0][tid] + red[1][1][tid] + red[1][2][tid] + red[1][3][tid];
        const float m2 = fmaxf(fmaxf(red[0][0][tid], red[0][1][tid]),
                               fmaxf(red[0][2][tid], red[0][3][tid]));
        cs[hb + rbase + tid] = -(m2 * LOG2E + __log2f(s));
    }
}

// ---------------------------------------------------------------------------
// Fused attention apply. Wh^T chunks (64f x 64j bf16) DOUBLE-buffered in LDS,
// ONE barrier per chunk: [prefetch regs c+1][compute from buf c&1]
// [write buf (c+1)&1][barrier]. Write target's last readers ran in iter c-1,
// separated by that iter's barrier; within an iter the two halves are
// disjoint. Loop fully unrolled (NCH constexpr) so buffer index is static.
// P-gen reduced to 4 VALU + 1 trans/elem: s2 staged pre-scaled by log2e,
// per-row A = s1L+cc, B = 0.2*s1L+cc; ev = fmax(A+t, fma(t,0.2,B)).
// ---------------------------------------------------------------------------
template <int H, int JQ, int OUT_BF16>
__global__ __launch_bounds__(256, 4) void apply_kernel(
    const ushort_t* __restrict__ WhbT, const int S,
    const float* __restrict__ s1, const float* __restrict__ s2,
    const float* __restrict__ cs, const unsigned* __restrict__ bm32,
    void* __restrict__ outp) {
    constexpr int JLEN = NN / JQ;
    constexpr int BW = JLEN / 32;
    constexpr int NCH = JLEN / 64;
    constexpr int OB = OUT_BF16 ? (64 * 72 * 2) : (64 * 68 * 4);
    constexpr int SB = 2 * 8192;
    constexpr int UBUF = (SB > OB) ? SB : OB;

    __shared__ __align__(16) float s2s[JLEN];
    __shared__ unsigned bs[64][BW + 1];
    __shared__ __align__(16) char ubuf[UBUF];
    auto stage = (unsigned (*)[64][32])ubuf;       // [2][64 f-rows][8 slots x 4 u32]

    const int Bk = blockIdx.x;
    const int lid = (Bk & 7) * 128 + (Bk >> 3);    // XCD-contiguous logical id
    const int it = lid & 15;
    const int b  = (lid >> 4) & 15;
    const int z  = lid >> 8;
    const int h  = (H > 1) ? z : 0;
    const int jq = (JQ > 1) ? z : 0;
    const int j0g = jq * JLEN;

    const int tid = threadIdx.x;
    const int w = tid >> 6, l = tid & 63;
    const int lo = l & 15, kg = l >> 4;
    const int iloc = w * 16 + lo;
    const int rbase = b * NN + it * 64;
    const int gi = rbase + iloc;
    const int hb = h * (BB * NN);

    const ushort_t* __restrict__ whb = WhbT + ((size_t)(b * S + h * FH)) * NN + j0g;

    const int r0 = tid >> 3, st = tid & 7;
    const int sw = (st ^ (r0 & 7)) * 4;
    const size_t ga = (size_t)r0 * NN + st * 8;
    const size_t gb = (size_t)(r0 + 32) * NN + st * 8;

    // chunk-0 prefetch (latency hidden under s2/bits staging)
    int4 cv0 = *(const int4*)(whb + ga);
    int4 cv1 = *(const int4*)(whb + gb);

    // stage s2 (pre-scaled by log2e) + adjacency bits
    const float* __restrict__ s2g = s2 + hb + b * NN + j0g;
    for (int k = tid; k < JLEN / 4; k += 256) {
        float4 v = *(const float4*)(s2g + k * 4);
        v.x *= LOG2E; v.y *= LOG2E; v.z *= LOG2E; v.w *= LOG2E;
        *(float4*)(s2s + k * 4) = v;
    }
    for (int idx = tid; idx < 64 * BW; idx += 256) {
        int r = idx / BW, wd = idx - r * BW;
        bs[r][wd] = bm32[(size_t)(rbase + r) * 32 + (j0g >> 5) + wd];
    }

    const float s1L = s1[hb + gi] * LOG2E;
    const float cc  = cs[hb + gi];
    const float Arow = s1L + cc;
    const float Brow = __builtin_fmaf(s1L, 0.2f, cc);

    f32x4 acc[4];
    #pragma unroll
    for (int fb = 0; fb < 4; ++fb) acc[fb] = (f32x4){0.f, 0.f, 0.f, 0.f};

    // write chunk 0 into buf 0; single barrier covers s2s/bs/stage0
    *(int4*)&stage[0][r0][sw] = cv0;
    *(int4*)&stage[0][r0 + 32][sw] = cv1;
    __syncthreads();

    #pragma unroll
    for (int c = 0; c < NCH; ++c) {
        if (c + 1 < NCH) {
            const ushort_t* src = whb + (c + 1) * 64;
            cv0 = *(const int4*)(src + ga);
            cv1 = *(const int4*)(src + gb);
        }
        #pragma unroll
        for (int ks = 0; ks < 2; ++ks) {
            const int kb = c * 64 + ks * 32 + kg * 8;
            const unsigned byte = (bs[iloc][c * 2 + ks] >> (kg * 8)) & 0xFF;
            const float4 sa = *(const float4*)(s2s + kb);
            const float4 sb = *(const float4*)(s2s + kb + 4);
            const float s2r[8] = {sa.x, sa.y, sa.z, sa.w, sb.x, sb.y, sb.z, sb.w};
            short8 bfr;
            #pragma unroll
            for (int e = 0; e < 8; ++e) {
                const float t = s2r[e];
                const float u = Arow + t;
                const float v = __builtin_fmaf(t, 0.2f, Brow);
                float ev = fmaxf(u, v);
                ev = ((byte >> e) & 1) ? ev : -1.0e5f;
                bfr[e] = (short)f2bf(__builtin_amdgcn_exp2f(ev));
            }
            #pragma unroll
            for (int fb = 0; fb < 4; ++fb) {
                const int row = fb * 16 + lo;
                const int slot = (ks * 4 + kg) ^ (row & 7);
                const short8 afr = *(const short8*)&stage[c & 1][row][slot * 4];
                acc[fb] = __builtin_amdgcn_mfma_f32_16x16x32_bf16(afr, bfr, acc[fb], 0, 0, 0);
            }
        }
        if (c + 1 < NCH) {
            *(int4*)&stage[(c + 1) & 1][r0][sw] = cv0;
            *(int4*)&stage[(c + 1) & 1][r0 + 32][sw] = cv1;
        }
        __syncthreads();
    }

    // lane (lo,kg) holds i = iloc, f = fb*16 + kg*4 + r
    if constexpr (OUT_BF16) {
        unsigned* ot = (unsigned*)ubuf;
        #pragma unroll
        for (int fb = 0; fb < 4; ++fb)
            #pragma unroll
            for (int rp = 0; rp < 2; ++rp) {
                unsigned lobf = f2bf(acc[fb][rp * 2]);
                unsigned hibf = f2bf(acc[fb][rp * 2 + 1]);
                ot[iloc * 36 + fb * 8 + kg * 2 + rp] = lobf | (hibf << 16);
            }
        __syncthreads();
        const int i2 = tid >> 2, ch = tid & 3;
        const short8 v0 = *(const short8*)((const short*)ubuf + i2 * 72 + ch * 16);
        const short8 v1 = *(const short8*)((const short*)ubuf + i2 * 72 + ch * 16 + 8);
        ushort_t* dst = (ushort_t*)outp + (size_t)(b * NN + it * 64 + i2) * 256 + h * FH + ch * 16;
        *(short8*)dst = v0;
        *(short8*)(dst + 8) = v1;
    } else {
        float* ot = (float*)ubuf;
        #pragma unroll
        for (int fb = 0; fb < 4; ++fb)
            #pragma unroll
            for (int r = 0; r < 4; ++r)
                ot[iloc * 68 + fb * 16 + kg * 4 + r] = acc[fb][r];
        __syncthreads();
        const int i2 = tid >> 2, ch = tid & 3;
        float* dst = (float*)outp + (size_t)jq * (BB * NN * FH)
                   + (size_t)(b * NN + it * 64 + i2) * FH + ch * 16;
        *(f32x4*)dst        = *(const f32x4*)(ot + i2 * 68 + ch * 16);
        *(f32x4*)(dst + 4)  = *(const f32x4*)(ot + i2 * 68 + ch * 16 + 4);
        *(f32x4*)(dst + 8)  = *(const f32x4*)(ot + i2 * 68 + ch * 16 + 8);
        *(f32x4*)(dst + 12) = *(const f32x4*)(ot + i2 * 68 + ch * 16 + 12);
    }
}

// ---------------------------------------------------------------------------
// Mean stage 1: 256 blocks (b, 64-row chunk) -> partial sums (with ELU).
// ---------------------------------------------------------------------------
__global__ __launch_bounds__(256) void mean1_kernel(const float* __restrict__ part,
                                                    float* __restrict__ partial) {
    const int b = blockIdx.x, ck = blockIdx.y;
    const int tid = threadIdx.x;
    const int f = tid & 63, g = tid >> 6;
    float acc = 0.f;
    #pragma unroll
    for (int i = g; i < 64; i += 4) {
        const size_t base = ((size_t)(b * NN + ck * 64 + i)) * FH + f;
        float v = part[base] + part[base + 1048576] + part[base + 2097152] + part[base + 3145728];
        v = (v > 0.f) ? v : (__builtin_amdgcn_exp2f(v * LOG2E) - 1.0f);
        acc += v;
    }
    __shared__ float r[4][64];
    r[g][f] = acc;
    __syncthreads();
    if (g == 0)
        partial[(b * 16 + ck) * FH + f] = r[0][f] + r[1][f] + r[2][f] + r[3][f];
}

// ---------------------------------------------------------------------------
// Mean stage 2: one block combines 16 chunk-partials per (b,f).
// ---------------------------------------------------------------------------
__global__ __launch_bounds__(1024) void mean2_kernel(const float* __restrict__ partial,
                                                     float* __restrict__ out) {
    const int t = threadIdx.x;
    const int b = t >> 6, f = t & 63;
    float s = 0.f;
    #pragma unroll
    for (int ck = 0; ck < 16; ++ck) s += partial[(b * 16 + ck) * FH + f];
    out[b * FH + f] = s * (1.0f / NN);
}

extern "C" void kernel_launch(void* const* d_in, const int* in_sizes, int n_in,
                              void* d_out, int out_size, void* d_ws, size_t ws_size,
                              hipStream_t stream) {
    const float* x       = (const float*)d_in[0];
    const int*   adj     = (const int*)d_in[1];
    const float* W_heads = (const float*)d_in[2];
    const float* a_heads = (const float*)d_in[3];
    const float* W_out   = (const float*)d_in[4];
    const float* a_out   = (const float*)d_in[5];
    float* out = (float*)d_out;
    float* f0  = (float*)d_ws;

    // workspace (float offsets). part(16MB) overlays hcat+WhbT1 (both dead).
    ushort_t* hcat  = (ushort_t*)f0;                     // [16384][256] bf16, 8 MB
    ushort_t* WhbT1 = (ushort_t*)(f0 + 2097152);         // [16][256][1024] bf16, 8 MB
    float*    part  = f0;                                // [4][16384][64] f32, 16 MB (after gemm2)
    ushort_t* WhbT2 = (ushort_t*)(f0 + 4194304);         // [16][64][1024] bf16, 2 MB
    u64*      bmask = (u64*)(f0 + 4718592);              // [16384][16] u64, 2 MB
    ushort_t* WbT1  = (ushort_t*)(f0 + 5242880);         // [256][256] bf16
    ushort_t* WbT2  = (ushort_t*)(f0 + 5275648);         // [64][256] bf16
    float*    s1_1  = f0 + 5283840;                      // [4][16384]
    float*    s2_1  = s1_1 + 65536;
    float*    cs_1  = s2_1 + 65536;
    float*    s1_2  = cs_1 + 65536;                      // [16384]
    float*    s2_2  = s1_2 + 16384;
    float*    cs_2  = s2_2 + 16384;
    float*    partial = cs_2 + 16384;                    // [16][16][64]

    dim3 blk(256);

    // shared pre-passes
    pack_kernel<<<dim3(BB * NN / 4), blk, 0, stream>>>(adj, bmask);
    packw_kernel<<<dim3(320), blk, 0, stream>>>(W_heads, W_out, WbT1, WbT2);

    // layer 1
    gemm_fused<0><<<dim3(4, 256), blk, 0, stream>>>(x, WbT1, a_heads, WhbT1, s1_1, s2_1, 256);
    stats_kernel<<<dim3(256, NH), blk, 0, stream>>>(s1_1, s2_1, (const unsigned*)bmask, cs_1);
    apply_kernel<NH, 1, 1><<<dim3(1024), blk, 0, stream>>>(WhbT1, 256, s1_1, s2_1, cs_1,
                                                           (const unsigned*)bmask, hcat);

    // layer 2
    gemm_fused<1><<<dim3(1, 256), blk, 0, stream>>>(hcat, WbT2, a_out, WhbT2, s1_2, s2_2, 64);
    stats_kernel<<<dim3(256, 1), blk, 0, stream>>>(s1_2, s2_2, (const unsigned*)bmask, cs_2);
    apply_kernel<1, 4, 0><<<dim3(1024), blk, 0, stream>>>(WhbT2, 64, s1_2, s2_2, cs_2,
                                                          (const unsigned*)bmask, part);

    // combine partials + elu + mean (two-stage)
    mean1_kernel<<<dim3(BB, 16), blk, 0, stream>>>(part, partial);
    mean2_kernel<<<dim3(1), dim3(1024), 0, stream>>>(partial, out);
}